// Round 10
// baseline (446.529 us; speedup 1.0000x reference)
//
#include <hip/hip_runtime.h>
#include <math.h>

// improvedDeformableLocalCrossAttention — fp32, algebraically restructured:
//   h = shift_feat @ W_off1  ==  P[gathered point] + Q[query]
//   attn logits = interp . qkh   (kills the Wk GEMM)
//   out_pre = Sum_k attn * (Sum_gs w * VW[i])  where VW = q_gslice @ Wv_gslice
// R10: all remaining 64x64 GEMMs -> 128x64 tiles (8x4 accs).
// R11: offset_assemble: branchless A&S erf, single-pass mean/var, float2 loads.
// R12: three_nn 4-chunk split + exact merge (88.8 -> 74.6).
// R13: offset_assemble 4-rows/wave interleave (86 -> 66; total -41us).
// R14: FAILED: float2 candidate loads changed FP contraction -> selection flips.
// R15-R17: three_nn config sweep: all 2x-invariant => issue-bound.
// R18: three_nn insert via v_min/v_med3: 73.9 -> 65.5 (matched; issue-bound).
// R19: REGRESSED (66->70.6): 8 rows/wave doubled ILP but occupancy 62->36
//      (VGPR 36->60); wave-level hiding was worth more. 4-row is the optimum
//      of that trade. NEW SIGNAL: FETCH 49.4MB vs 25MB live data => P-gather
//      L2 thrash is the stall source.
// R20: revert offset_assemble to R13 body (verbatim, bit-identical) + XCD
//      swizzle bn=(bid&7)*1024+(bid>>3): under round-robin dispatch each XCD
//      gets ALL blocks of one bg; that bg's P+Q panels (3MB) fit its 4MB L2
//      => gathers become L2 hits. Pure index permutation, zero numerics risk.

#define ATTN_SCALE 0.14433756729740643f  // 48^-0.5

// ---- workspace layout (4-byte element offsets) ----
#define OFF_IDX   0u          // int   [4096*16]
#define OFF_SC    65536u      // float [4096*3]
#define OFF_QP    77824u      // float [4096*384]
#define OFF_VOFF  1650688u    // float [4096*384]
#define OFF_P     3223552u    // float [8192*384]   (dead after offset_assemble; 3nn part_d)
#define OFF_Q     6369280u    // float [8192*384]   (dead after offset_assemble; 3nn part_i)
#define OFF_SP    9515008u    // float [8*16384*3]
#define OFF_W3    9908224u    // float [8*16384*3]
#define OFF_I3    10301440u   // int   [8*16384*3]
#define OFF_QKH   10694656u   // float [4096*8*384]
#define OFF_VW    23277568u   // float [8192*384]
#define OFF_OPRE  35860480u   // float [4096*384]
// 3nn partials: 131072 queries * 8 chunks * 3 = 3145728 elems each (exact fit in P / Q)
#define OFF_P3D   OFF_P
#define OFF_P3I   OFF_Q

// Branchless erf, Abramowitz-Stegun 7.1.26 (|abs err| <= 1.5e-7):
//   erf(z) ~= sign(z) * (1 - (a1 t + ... + a5 t^5) exp(-z^2)), t = 1/(1+p|z|)
__device__ __forceinline__ float fast_erff(float z) {
  float az = fabsf(z);
  float d = fmaf(0.3275911f, az, 1.0f);
  float t0 = __builtin_amdgcn_rcpf(d);
  float t = t0 * fmaf(-d, t0, 2.0f);               // one Newton step
  float e = __builtin_amdgcn_exp2f(z * z * -1.4426950408889634f);
  float p = fmaf(fmaf(fmaf(fmaf(1.061405429f, t, -1.453152027f),
                           t, 1.421413741f),
                      t, -0.284496736f),
                 t, 0.254829592f);
  float r = 1.0f - p * t * e;
  return __builtin_copysignf(r, z);
}

// ---------------- kernel 1: kNN (K=16) + sc = 0.5*(max-min) of neighbor positions ----
__global__ __launch_bounds__(64) void knn_kernel(const float* __restrict__ qpos,
                                                 int* __restrict__ idx_out,
                                                 float* __restrict__ sc_out) {
  int bn = blockIdx.x;               // b*1024+n
  int b = bn >> 10, n = bn & 1023;
  int lane = threadIdx.x;
  const float* pb = qpos + (size_t)b * 1024 * 3;
  float qx = pb[n * 3 + 0], qy = pb[n * 3 + 1], qz = pb[n * 3 + 2];
  float qq = qx * qx + qy * qy + qz * qz;
  float d2[16];
#pragma unroll
  for (int u = 0; u < 16; ++u) {
    int p = lane + 64 * u;
    float px = pb[p * 3 + 0], py = pb[p * 3 + 1], pz = pb[p * 3 + 2];
    float pp = px * px + py * py + pz * pz;
    float dt = qx * px + qy * py + qz * pz;
    d2[u] = (qq + pp) - 2.0f * dt;   // mimic reference expansion form
  }
  float mnx = 3.4e38f, mny = 3.4e38f, mnz = 3.4e38f;
  float mxx = -3.4e38f, mxy = -3.4e38f, mxz = -3.4e38f;
  for (int r = 0; r < 16; ++r) {
    float best = d2[0]; int bu = 0;
#pragma unroll
    for (int u = 1; u < 16; ++u) { if (d2[u] < best) { best = d2[u]; bu = u; } }
    int bidx = lane + 64 * bu;
#pragma unroll
    for (int off = 32; off > 0; off >>= 1) {
      float ov = __shfl_xor(best, off);
      int oi = __shfl_xor(bidx, off);
      if (ov < best || (ov == best && oi < bidx)) { best = ov; bidx = oi; }
    }
    if ((bidx & 63) == lane) d2[bidx >> 6] = 3.4e38f;
    float wx = pb[bidx * 3 + 0], wy = pb[bidx * 3 + 1], wz = pb[bidx * 3 + 2];
    mnx = fminf(mnx, wx); mny = fminf(mny, wy); mnz = fminf(mnz, wz);
    mxx = fmaxf(mxx, wx); mxy = fmaxf(mxy, wy); mxz = fmaxf(mxz, wz);
    if (lane == 0) idx_out[bn * 16 + r] = bidx;
  }
  if (lane == 0) {
    sc_out[bn * 3 + 0] = 0.5f * (mxx - mnx);
    sc_out[bn * 3 + 1] = 0.5f * (mxy - mny);
    sc_out[bn * 3 + 2] = 0.5f * (mxz - mnz);
  }
}

// ---------------- kernel 2: qp/voff dual-B GEMM, 128x64 tile -------------------------
__global__ __launch_bounds__(256) void gemm_qp_voff(const float* __restrict__ Aq,
    const float* __restrict__ W1, const float* __restrict__ W2,
    float* __restrict__ O1, float* __restrict__ O2) {
  __shared__ float As[16 * 132];
  __shared__ float Bs1[16 * 64];
  __shared__ float Bs2[16 * 64];
  int tid = threadIdx.x;
  int m0 = blockIdx.x * 128, n0 = blockIdx.y * 64;
  int arow = tid >> 1, akq = (tid & 1) * 8;
  int lk = tid >> 4, ln4 = (tid & 15) * 4;
  int tx = tid & 15, ty = tid >> 4;
  float a11[4][4] = {{0.f}}, a21[4][4] = {{0.f}};
  float a12[4][4] = {{0.f}}, a22[4][4] = {{0.f}};
  for (int k0 = 0; k0 < 384; k0 += 16) {
    float4 a0 = *(const float4*)(Aq + (size_t)(m0 + arow) * 384 + k0 + akq);
    float4 a1 = *(const float4*)(Aq + (size_t)(m0 + arow) * 384 + k0 + akq + 4);
    float4 b1 = *(const float4*)(W1 + (size_t)(k0 + lk) * 384 + n0 + ln4);
    float4 b2 = *(const float4*)(W2 + (size_t)(k0 + lk) * 384 + n0 + ln4);
    __syncthreads();
    As[(akq + 0) * 132 + arow] = a0.x; As[(akq + 1) * 132 + arow] = a0.y;
    As[(akq + 2) * 132 + arow] = a0.z; As[(akq + 3) * 132 + arow] = a0.w;
    As[(akq + 4) * 132 + arow] = a1.x; As[(akq + 5) * 132 + arow] = a1.y;
    As[(akq + 6) * 132 + arow] = a1.z; As[(akq + 7) * 132 + arow] = a1.w;
    *(float4*)(Bs1 + lk * 64 + ln4) = b1;
    *(float4*)(Bs2 + lk * 64 + ln4) = b2;
    __syncthreads();
#pragma unroll
    for (int k = 0; k < 16; ++k) {
      float4 av0 = *(const float4*)(As + k * 132 + ty * 4);
      float4 av1 = *(const float4*)(As + k * 132 + 64 + ty * 4);
      float4 bv1 = *(const float4*)(Bs1 + k * 64 + tx * 4);
      float4 bv2 = *(const float4*)(Bs2 + k * 64 + tx * 4);
      float x0[4] = {av0.x, av0.y, av0.z, av0.w};
      float x1[4] = {av1.x, av1.y, av1.z, av1.w};
      float c1[4] = {bv1.x, bv1.y, bv1.z, bv1.w};
      float c2[4] = {bv2.x, bv2.y, bv2.z, bv2.w};
#pragma unroll
      for (int i = 0; i < 4; ++i)
#pragma unroll
        for (int j = 0; j < 4; ++j) {
          a11[i][j] = fmaf(x0[i], c1[j], a11[i][j]);
          a21[i][j] = fmaf(x1[i], c1[j], a21[i][j]);
          a12[i][j] = fmaf(x0[i], c2[j], a12[i][j]);
          a22[i][j] = fmaf(x1[i], c2[j], a22[i][j]);
        }
    }
  }
#pragma unroll
  for (int i = 0; i < 4; ++i) {
    size_t rA = (size_t)(m0 + ty * 4 + i);
    size_t rB = (size_t)(m0 + 64 + ty * 4 + i);
    *(float4*)(O1 + rA * 384 + n0 + tx * 4) = make_float4(a11[i][0], a11[i][1], a11[i][2], a11[i][3]);
    *(float4*)(O1 + rB * 384 + n0 + tx * 4) = make_float4(a21[i][0], a21[i][1], a21[i][2], a21[i][3]);
    *(float4*)(O2 + rA * 384 + n0 + tx * 4) = make_float4(a12[i][0], a12[i][1], a12[i][2], a12[i][3]);
    *(float4*)(O2 + rB * 384 + n0 + tx * 4) = make_float4(a22[i][0], a22[i][1], a22[i][2], a22[i][3]);
  }
}

// ---------------- kernel 3: 3-way K=192 group-sliced GEMM, 128x64 tile ---------------
__global__ __launch_bounds__(256) void gemm_pq3(const float* __restrict__ voff,
    const float* __restrict__ qp, const float* __restrict__ qin,
    const float* __restrict__ Woff1, const float* __restrict__ boff1,
    const float* __restrict__ Wv,
    float* __restrict__ P, float* __restrict__ Q, float* __restrict__ VW) {
  __shared__ float As[16 * 132];
  __shared__ float Bs[16 * 64];
  int tid = threadIdx.x;
  int m0 = blockIdx.x * 128, n0 = blockIdx.y * 64, z = blockIdx.z;
  int bg = m0 >> 10; int b = bg >> 1; int g = bg & 1; int ml0 = m0 & 1023;
  const float* Abase; const float* Bbase; const float* bias; float* Out; int bog;
  if (z == 0)      { Abase = voff; Bbase = Woff1;             bias = nullptr; Out = P;  bog = 0; }
  else if (z == 1) { Abase = qp;   Bbase = Woff1 + 192 * 384; bias = boff1;   Out = Q;  bog = 0; }
  else             { Abase = qin;  Bbase = Wv;                bias = nullptr; Out = VW; bog = 192 * 384; }
  const float* A = Abase + (size_t)b * 1024 * 384 + g * 192;
  const float* B = Bbase + (size_t)g * bog;
  int arow = tid >> 1, akq = (tid & 1) * 8;
  int lk = tid >> 4, ln4 = (tid & 15) * 4;
  int tx = tid & 15, ty = tid >> 4;
  float accA[4][4] = {{0.f}}, accB[4][4] = {{0.f}};
  for (int k0 = 0; k0 < 192; k0 += 16) {
    float4 a0 = *(const float4*)(A + (size_t)(ml0 + arow) * 384 + k0 + akq);
    float4 a1 = *(const float4*)(A + (size_t)(ml0 + arow) * 384 + k0 + akq + 4);
    float4 b4 = *(const float4*)(B + (size_t)(k0 + lk) * 384 + n0 + ln4);
    __syncthreads();
    As[(akq + 0) * 132 + arow] = a0.x; As[(akq + 1) * 132 + arow] = a0.y;
    As[(akq + 2) * 132 + arow] = a0.z; As[(akq + 3) * 132 + arow] = a0.w;
    As[(akq + 4) * 132 + arow] = a1.x; As[(akq + 5) * 132 + arow] = a1.y;
    As[(akq + 6) * 132 + arow] = a1.z; As[(akq + 7) * 132 + arow] = a1.w;
    *(float4*)(Bs + lk * 64 + ln4) = b4;
    __syncthreads();
#pragma unroll
    for (int k = 0; k < 16; ++k) {
      float4 av0 = *(const float4*)(As + k * 132 + ty * 4);
      float4 av1 = *(const float4*)(As + k * 132 + 64 + ty * 4);
      float4 bv = *(const float4*)(Bs + k * 64 + tx * 4);
      float a0v[4] = {av0.x, av0.y, av0.z, av0.w};
      float a1v[4] = {av1.x, av1.y, av1.z, av1.w};
      float c[4] = {bv.x, bv.y, bv.z, bv.w};
#pragma unroll
      for (int i = 0; i < 4; ++i)
#pragma unroll
        for (int j = 0; j < 4; ++j) {
          accA[i][j] = fmaf(a0v[i], c[j], accA[i][j]);
          accB[i][j] = fmaf(a1v[i], c[j], accB[i][j]);
        }
    }
  }
  float bb[4] = {0.f, 0.f, 0.f, 0.f};
  if (bias) {
    bb[0] = bias[n0 + tx * 4 + 0]; bb[1] = bias[n0 + tx * 4 + 1];
    bb[2] = bias[n0 + tx * 4 + 2]; bb[3] = bias[n0 + tx * 4 + 3];
  }
#pragma unroll
  for (int i = 0; i < 4; ++i) {
    size_t rowA = (size_t)(m0 + ty * 4 + i);
    size_t rowB = (size_t)(m0 + 64 + ty * 4 + i);
    *(float4*)(Out + rowA * 384 + n0 + tx * 4) =
        make_float4(accA[i][0] + bb[0], accA[i][1] + bb[1], accA[i][2] + bb[2], accA[i][3] + bb[3]);
    *(float4*)(Out + rowB * 384 + n0 + tx * 4) =
        make_float4(accB[i][0] + bb[0], accB[i][1] + bb[1], accB[i][2] + bb[2], accB[i][3] + bb[3]);
  }
}

// ---------------- kernel 4: h = P[idx]+Q -> LN -> GELU -> @W_off2 -> tanh -> shift ---
// R13 body (verbatim; 4 rows/wave, 256 threads) + R20 XCD swizzle: under
// round-robin dispatch, bn=(bid&7)*1024+(bid>>3) gives each XCD all blocks of
// one bg, whose P+Q panels (3MB) fit its 4MB L2. Index permutation only.
__global__ __launch_bounds__(256) void offset_assemble(const float* __restrict__ P,
    const float* __restrict__ Q, const int* __restrict__ idx,
    const float* __restrict__ lng, const float* __restrict__ lnb,
    const float* __restrict__ W2, const float* __restrict__ qpos,
    const float* __restrict__ sc, float* __restrict__ sp) {
  int bid = blockIdx.x;
  int bn = ((bid & 7) << 10) | (bid >> 3);   // bg*1024 + n  (8192 blocks)
  int wid = threadIdx.x >> 6, lane = threadIdx.x & 63;
  int n = bn & 1023, bg = bn >> 10, b = bg >> 1;
  int k0 = wid * 4;
  const int* idxr = idx + (((b << 10) + n) << 4) + k0;
  int mi[4];
#pragma unroll
  for (int r = 0; r < 4; ++r) mi[r] = idxr[r];
  const float* Qr = Q + ((size_t)bg * 1024 + n) * 384;
  const float* Pr[4];
#pragma unroll
  for (int r = 0; r < 4; ++r) Pr[r] = P + ((size_t)bg * 1024 + mi[r]) * 384;

  float h[4][6];
  float s[4] = {0.f, 0.f, 0.f, 0.f}, s2[4] = {0.f, 0.f, 0.f, 0.f};
#pragma unroll
  for (int u = 0; u < 3; ++u) {
    int c = 2 * lane + 128 * u;
    float2 qv = *(const float2*)(Qr + c);
#pragma unroll
    for (int r = 0; r < 4; ++r) {
      float2 pv = *(const float2*)(Pr[r] + c);
      float h0 = pv.x + qv.x, h1 = pv.y + qv.y;
      h[r][2 * u] = h0; h[r][2 * u + 1] = h1;
      s[r] += h0 + h1;
      s2[r] = fmaf(h0, h0, s2[r]);
      s2[r] = fmaf(h1, h1, s2[r]);
    }
  }
#pragma unroll
  for (int off = 32; off > 0; off >>= 1) {  // 8 interleaved butterflies
#pragma unroll
    for (int r = 0; r < 4; ++r) {
      s[r]  += __shfl_xor(s[r], off);
      s2[r] += __shfl_xor(s2[r], off);
    }
  }
  float mu[4], rstd[4];
#pragma unroll
  for (int r = 0; r < 4; ++r) {
    mu[r] = s[r] * (1.0f / 384.0f);
    float var = s2[r] * (1.0f / 384.0f) - mu[r] * mu[r];
    rstd[r] = 1.0f / sqrtf(var + 1e-5f);
  }
  float o0[4] = {0.f, 0.f, 0.f, 0.f}, o1[4] = {0.f, 0.f, 0.f, 0.f}, o2[4] = {0.f, 0.f, 0.f, 0.f};
#pragma unroll
  for (int u = 0; u < 3; ++u) {
    int c = 2 * lane + 128 * u;
    float2 gv  = *(const float2*)(lng + c);
    float2 bv  = *(const float2*)(lnb + c);
    float2 w01 = *(const float2*)(W2 + (size_t)c * 3);      // [c][0],[c][1]
    float2 w23 = *(const float2*)(W2 + (size_t)c * 3 + 2);  // [c][2],[c+1][0]
    float2 w45 = *(const float2*)(W2 + (size_t)c * 3 + 4);  // [c+1][1],[c+1][2]
#pragma unroll
    for (int r = 0; r < 4; ++r) {
      float x0 = fmaf((h[r][2 * u] - mu[r]) * rstd[r], gv.x, bv.x);
      float x1 = fmaf((h[r][2 * u + 1] - mu[r]) * rstd[r], gv.y, bv.y);
      float g0 = x0 * fmaf(fast_erff(x0 * 0.70710678118654752f), 0.5f, 0.5f);
      float g1 = x1 * fmaf(fast_erff(x1 * 0.70710678118654752f), 0.5f, 0.5f);
      o0[r] = fmaf(g0, w01.x, o0[r]); o1[r] = fmaf(g0, w01.y, o1[r]); o2[r] = fmaf(g0, w23.x, o2[r]);
      o0[r] = fmaf(g1, w23.y, o0[r]); o1[r] = fmaf(g1, w45.x, o1[r]); o2[r] = fmaf(g1, w45.y, o2[r]);
    }
  }
#pragma unroll
  for (int off = 32; off > 0; off >>= 1) {  // 12 interleaved butterflies
#pragma unroll
    for (int r = 0; r < 4; ++r) {
      o0[r] += __shfl_xor(o0[r], off);
      o1[r] += __shfl_xor(o1[r], off);
      o2[r] += __shfl_xor(o2[r], off);
    }
  }
  if (lane < 3) {
    float scv = sc[(((b << 10) + n)) * 3 + lane];
#pragma unroll
    for (int r = 0; r < 4; ++r) {
      float o = (lane == 0) ? o0[r] : ((lane == 1) ? o1[r] : o2[r]);
      float off = tanhf(o);
      float p = qpos[((size_t)b * 1024 + mi[r]) * 3 + lane];
      int row = (bn << 4) + k0 + r;       // (bg*1024+n)*16+k
      sp[(size_t)row * 3 + lane] = p + off * scv;
    }
  }
}

// ---------------- kernel 5a: three_nn partial — 8 chunks of 128, 2 chains, 2048 blks -
// R18: value-half of the sorted-triple insert via v_min/v_med3 (bitwise-exact
// selection); index compares verbatim strict-<. Distance exprs and candidate
// load shape untouched (R14 lesson). Geometry frozen at R17.
__global__ __launch_bounds__(256) void three_nn_part(const float* __restrict__ spos,
    const float* __restrict__ qpos, float* __restrict__ part_d, int* __restrict__ part_i) {
  __shared__ float px[128], py[128], pz[128], pp[128];
  int bid = blockIdx.x;             // bg(3b) | qg(5b) | chunk(3b)
  int bg = bid >> 8;
  int qg = (bid >> 3) & 31;
  int c  = bid & 7;
  int b = bg >> 1;
  int j0 = c << 7;
  const float* pb = qpos + (size_t)b * 1024 * 3;
  int tid = threadIdx.x;
  if (tid < 128) {
    int j = j0 + tid;
    float x = pb[j * 3 + 0], y = pb[j * 3 + 1], z = pb[j * 3 + 2];
    px[tid] = x; py[tid] = y; pz[tid] = z; pp[tid] = x * x + y * y + z * z;
  }
  __syncthreads();
  int m0 = qg * 512;
  int mA = m0 + tid;
  int mB = mA + 256;
  const float* spA = spos + ((size_t)bg * 16384 + mA) * 3;
  const float* spB = spos + ((size_t)bg * 16384 + mB) * 3;
  float sxA = spA[0], syA = spA[1], szA = spA[2];
  float sxB = spB[0], syB = spB[1], szB = spB[2];
  float qqA = sxA * sxA + syA * syA + szA * szA;
  float qqB = sxB * sxB + syB * syB + szB * szB;
  float d0A = 3.4e38f, d1A = 3.4e38f, d2A = 3.4e38f; int i0A = 0, i1A = 0, i2A = 0;
  float d0B = 3.4e38f, d1B = 3.4e38f, d2B = 3.4e38f; int i0B = 0, i1B = 0, i2B = 0;
#pragma unroll 8
  for (int jj = 0; jj < 128; ++jj) {
    int j = j0 + jj;
    float cx = px[jj], cy = py[jj], cz = pz[jj], cw = pp[jj];
    float dtA = sxA * cx + syA * cy + szA * cz;
    float dA = (qqA + cw) - 2.0f * dtA;
    float dtB = sxB * cx + syB * cy + szB * cz;
    float dB = (qqB + cw) - 2.0f * dtB;
    {
      bool c0 = dA < d0A, c1 = dA < d1A, c2 = dA < d2A;
      int   ni2 = c1 ? i1A : (c2 ? j : i2A);
      int   ni1 = c0 ? i0A : (c1 ? j : i1A);
      float nd2 = __builtin_amdgcn_fmed3f(d1A, d2A, dA);  // == c1?d1:(c2?dA:d2)
      float nd1 = __builtin_amdgcn_fmed3f(d0A, d1A, dA);  // == c0?d0:(c1?dA:d1)
      d0A = fminf(d0A, dA);  i0A = c0 ? j : i0A;
      d1A = nd1; i1A = ni1; d2A = nd2; i2A = ni2;
    }
    {
      bool c0 = dB < d0B, c1 = dB < d1B, c2 = dB < d2B;
      int   ni2 = c1 ? i1B : (c2 ? j : i2B);
      int   ni1 = c0 ? i0B : (c1 ? j : i1B);
      float nd2 = __builtin_amdgcn_fmed3f(d1B, d2B, dB);
      float nd1 = __builtin_amdgcn_fmed3f(d0B, d1B, dB);
      d0B = fminf(d0B, dB);  i0B = c0 ? j : i0B;
      d1B = nd1; i1B = ni1; d2B = nd2; i2B = ni2;
    }
  }
  {
    size_t base = (((size_t)bg * 8 + c) * 16384 + mA) * 3;
    part_d[base + 0] = d0A; part_d[base + 1] = d1A; part_d[base + 2] = d2A;
    part_i[base + 0] = i0A; part_i[base + 1] = i1A; part_i[base + 2] = i2A;
  }
  {
    size_t base = (((size_t)bg * 8 + c) * 16384 + mB) * 3;
    part_d[base + 0] = d0B; part_d[base + 1] = d1B; part_d[base + 2] = d2B;
    part_i[base + 0] = i0B; part_i[base + 1] = i1B; part_i[base + 2] = i2B;
  }
}

// ---------------- kernel 5b: three_nn merge — insert 8 chunk triples in order --------
// Inserting each chunk's sorted triple (chunk order, then slot order) with strict-<
// and incumbent-wins reproduces the sequential scan's (d, scan-position) ordering
// exactly. Epilogue expressions verbatim from the old kernel.
__global__ __launch_bounds__(256) void three_nn_merge(const float* __restrict__ part_d,
    const int* __restrict__ part_i, float* __restrict__ w3, int* __restrict__ i3) {
  int q = blockIdx.x * 256 + threadIdx.x;   // 0..131071: bg*16384+m
  int bg = q >> 14, m = q & 16383;
  size_t pb = (((size_t)bg * 8) * 16384 + m) * 3;
  float D0 = part_d[pb + 0], D1 = part_d[pb + 1], D2 = part_d[pb + 2];
  int   I0 = part_i[pb + 0], I1 = part_i[pb + 1], I2 = part_i[pb + 2];
#pragma unroll
  for (int c = 1; c < 8; ++c) {
    size_t base = (((size_t)bg * 8 + c) * 16384 + m) * 3;
#pragma unroll
    for (int s = 0; s < 3; ++s) {
      float dv = part_d[base + s];
      int   iv = part_i[base + s];
      bool c0 = dv < D0, c1 = dv < D1, c2 = dv < D2;
      float nd2 = c1 ? D1 : (c2 ? dv : D2);
      int   ni2 = c1 ? I1 : (c2 ? iv : I2);
      float nd1 = c0 ? D0 : (c1 ? dv : D1);
      int   ni1 = c0 ? I0 : (c1 ? iv : I1);
      D0 = c0 ? dv : D0;  I0 = c0 ? iv : I0;
      D1 = nd1; I1 = ni1; D2 = nd2; I2 = ni2;
    }
  }
  float t0 = sqrtf(fmaxf(D0, 0.f)), t1 = sqrtf(fmaxf(D1, 0.f)), t2 = sqrtf(fmaxf(D2, 0.f));
  float r0 = 1.0f / (t0 + 1e-8f), r1 = 1.0f / (t1 + 1e-8f), r2 = 1.0f / (t2 + 1e-8f);
  float inv = 1.0f / (r0 + r1 + r2);
  size_t base = ((size_t)bg * 16384 + m) * 3;
  w3[base + 0] = r0 * inv; w3[base + 1] = r1 * inv; w3[base + 2] = r2 * inv;
  i3[base + 0] = I0; i3[base + 1] = I1; i3[base + 2] = I2;
}

// ---------------- kernel 6: qkh GEMM, 128x64 tile (K=48 per head) --------------------
__global__ __launch_bounds__(256) void gemm_qkh(const float* __restrict__ qp,
    const float* __restrict__ Wk, float* __restrict__ qkh) {
  __shared__ float As[16 * 132];
  __shared__ float Bs[16 * 68];
  int tid = threadIdx.x;
  int m0 = blockIdx.x * 128, c0 = blockIdx.y * 64, h = blockIdx.z;
  int arow = tid >> 1, akq = (tid & 1) * 8;
  int lm = tid >> 2, lq = (tid & 3) * 4;
  int tx = tid & 15, ty = tid >> 4;
  float accA[4][4] = {{0.f}}, accB[4][4] = {{0.f}};
  for (int k0 = 0; k0 < 48; k0 += 16) {
    float4 a0 = *(const float4*)(qp + (size_t)(m0 + arow) * 384 + h * 48 + k0 + akq);
    float4 a1 = *(const float4*)(qp + (size_t)(m0 + arow) * 384 + h * 48 + k0 + akq + 4);
    float4 b4 = *(const float4*)(Wk + (size_t)(c0 + lm) * 384 + h * 48 + k0 + lq);
    __syncthreads();
    As[(akq + 0) * 132 + arow] = a0.x; As[(akq + 1) * 132 + arow] = a0.y;
    As[(akq + 2) * 132 + arow] = a0.z; As[(akq + 3) * 132 + arow] = a0.w;
    As[(akq + 4) * 132 + arow] = a1.x; As[(akq + 5) * 132 + arow] = a1.y;
    As[(akq + 6) * 132 + arow] = a1.z; As[(akq + 7) * 132 + arow] = a1.w;
    Bs[(lq + 0) * 68 + lm] = b4.x; Bs[(lq + 1) * 68 + lm] = b4.y;
    Bs[(lq + 2) * 68 + lm] = b4.z; Bs[(lq + 3) * 68 + lm] = b4.w;
    __syncthreads();
#pragma unroll
    for (int k = 0; k < 16; ++k) {
      float4 av0 = *(const float4*)(As + k * 132 + ty * 4);
      float4 av1 = *(const float4*)(As + k * 132 + 64 + ty * 4);
      float4 bv = *(const float4*)(Bs + k * 68 + tx * 4);
      float a0v[4] = {av0.x, av0.y, av0.z, av0.w};
      float a1v[4] = {av1.x, av1.y, av1.z, av1.w};
      float c[4] = {bv.x, bv.y, bv.z, bv.w};
#pragma unroll
      for (int i = 0; i < 4; ++i)
#pragma unroll
        for (int j = 0; j < 4; ++j) {
          accA[i][j] = fmaf(a0v[i], c[j], accA[i][j]);
          accB[i][j] = fmaf(a1v[i], c[j], accB[i][j]);
        }
    }
  }
#pragma unroll
  for (int i = 0; i < 4; ++i) {
    size_t rowA = (size_t)(m0 + ty * 4 + i);
    size_t rowB = (size_t)(m0 + 64 + ty * 4 + i);
    *(float4*)(qkh + (rowA * 8 + h) * 384 + c0 + tx * 4) =
        make_float4(accA[i][0], accA[i][1], accA[i][2], accA[i][3]);
    *(float4*)(qkh + (rowB * 8 + h) * 384 + c0 + tx * 4) =
        make_float4(accB[i][0], accB[i][1], accB[i][2], accB[i][3]);
  }
}

// ---------------- kernel 7: fused interp + logits + softmax + out_pre ----------------
__global__ __launch_bounds__(256) void attn_fuse2(const float* __restrict__ v,
    const float* __restrict__ w3, const int* __restrict__ i3,
    const float* __restrict__ qkh, const float* __restrict__ VW,
    float* __restrict__ opre) {
  __shared__ float A[16 * 388];      // interp rows [k][c]
  __shared__ float Bv[16 * 388];     // interpVW rows [k][c']
  __shared__ float wk[16][2][3];
  __shared__ int ik[16][2][3];
  __shared__ float attnw[8 * 16];
  __shared__ float lpart[2][128];
  int tid = threadIdx.x;
  // XCD-aware swizzle: batch b -> XCD pair {2b, 2b+1} (round-robin dispatch assumed)
  int blk = blockIdx.x;
  int b = (blk & 7) >> 1;
  int n = ((blk & 1) << 9) | (blk >> 3);
  int bn = (b << 10) | n;
  if (tid < 96) {
    int k = tid / 6; int rem = tid % 6; int g = rem / 3; int s = rem % 3;
    size_t base = ((size_t)(b * 2 + g) * 16384 + n * 16 + k) * 3 + s;
    wk[k][g][s] = w3[base];
    ik[k][g][s] = i3[base];
  }
  __syncthreads();
  {  // build interp rows A[k][c] and interpVW rows Bv[k][c']; chunks c=(tid&15)*4+64u
    int r = tid >> 4;
    int cL = (tid & 15) * 4;
    const float* vr[2][3]; const float* wr[2][3];
#pragma unroll
    for (int g = 0; g < 2; ++g)
#pragma unroll
      for (int s = 0; s < 3; ++s) {
        vr[g][s] = v + ((size_t)b * 1024 + ik[r][g][s]) * 384;
        wr[g][s] = VW + ((size_t)(b * 2 + g) * 1024 + ik[r][g][s]) * 384;
      }
    float u0 = wk[r][0][0], u1 = wk[r][0][1], u2 = wk[r][0][2];
    float y0 = wk[r][1][0], y1 = wk[r][1][1], y2 = wk[r][1][2];
#pragma unroll
    for (int u = 0; u < 6; ++u) {
      int c = cL + 64 * u;
      int g = (u >= 3) ? 1 : 0;
      float w0 = wk[r][g][0], w1 = wk[r][g][1], w2 = wk[r][g][2];
      float4 f0 = *(const float4*)(vr[g][0] + c);
      float4 f1 = *(const float4*)(vr[g][1] + c);
      float4 f2 = *(const float4*)(vr[g][2] + c);
      float4 o;
      o.x = w0 * f0.x + w1 * f1.x + w2 * f2.x;
      o.y = w0 * f0.y + w1 * f1.y + w2 * f2.y;
      o.z = w0 * f0.z + w1 * f1.z + w2 * f2.z;
      o.w = w0 * f0.w + w1 * f1.w + w2 * f2.w;
      *(float4*)(A + r * 388 + c) = o;
      float4 a0 = *(const float4*)(wr[0][0] + c);
      float4 a1 = *(const float4*)(wr[0][1] + c);
      float4 a2 = *(const float4*)(wr[0][2] + c);
      float4 b0 = *(const float4*)(wr[1][0] + c);
      float4 b1 = *(const float4*)(wr[1][1] + c);
      float4 b2 = *(const float4*)(wr[1][2] + c);
      float4 p;
      p.x = u0 * a0.x + u1 * a1.x + u2 * a2.x + y0 * b0.x + y1 * b1.x + y2 * b2.x;
      p.y = u0 * a0.y + u1 * a1.y + u2 * a2.y + y0 * b0.y + y1 * b1.y + y2 * b2.y;
      p.z = u0 * a0.z + u1 * a1.z + u2 * a2.z + y0 * b0.z + y1 * b1.z + y2 * b2.z;
      p.w = u0 * a0.w + u1 * a1.w + u2 * a2.w + y0 * b0.w + y1 * b1.w + y2 * b2.w;
      *(float4*)(Bv + r * 388 + c) = p;
    }
  }
  __syncthreads();
  {  // logits with all 256 threads: (k,h,half) half-dots, then combine
    int r = tid & 15, h = (tid >> 4) & 7, half = tid >> 7;
    const float* qr = qkh + ((size_t)bn * 8 + h) * 384 + half * 192;
    const float* ar = A + r * 388 + half * 192;
    float acc = 0.f;
    for (int c = 0; c < 192; c += 4) {
      float4 av = *(const float4*)(ar + c);
      float4 qv = *(const float4*)(qr + c);
      acc += av.x * qv.x + av.y * qv.y + av.z * qv.z + av.w * qv.w;
    }
    lpart[half][h * 16 + r] = acc;
  }
  __syncthreads();
  if (tid < 128) attnw[tid] = (lpart[0][tid] + lpart[1][tid]) * ATTN_SCALE;
  __syncthreads();
  if (tid < 8) {  // softmax over k
    int h = tid;
    float m = -3.4e38f;
    for (int k = 0; k < 16; ++k) m = fmaxf(m, attnw[h * 16 + k]);
    float s = 0.f;
    for (int k = 0; k < 16; ++k) { float e = expf(attnw[h * 16 + k] - m); attnw[h * 16 + k] = e; s += e; }
    float inv = 1.0f / s;
    for (int k = 0; k < 16; ++k) attnw[h * 16 + k] *= inv;
  }
  __syncthreads();
  {  // out_pre[c'] = sum_k attn[h(c'),k] * Bv[k][c']
#pragma unroll
    for (int u = 0; u < 2; ++u) {
      int c = tid + 256 * u;
      if (c < 384) {
        int h = c / 48;
        float s = 0.f;
#pragma unroll
        for (int k = 0; k < 16; ++k) s = fmaf(attnw[h * 16 + k], Bv[k * 388 + c], s);
        opre[(size_t)bn * 384 + c] = s;
      }
    }
  }
}

// ---------------- kernel 9: out = out_pre @ Wp + bp, 128x64 tile ---------------------
__global__ __launch_bounds__(256) void gemm_final(const float* __restrict__ Ain,
    const float* __restrict__ Wp, const float* __restrict__ bp,
    float* __restrict__ Out) {
  __shared__ float As[16 * 132];
  __shared__ float Bs[16 * 64];
  int tid = threadIdx.x;
  int m0 = blockIdx.x * 128, n0 = blockIdx.y * 64;
  int arow = tid >> 1, akq = (tid & 1) * 8;
  int lk = tid >> 4, ln4 = (tid & 15) * 4;
  int tx = tid & 15, ty = tid >> 4;
  float accA[4][4] = {{0.f}}, accB[4][4] = {{0.f}};
  for (int k0 = 0; k0 < 384; k0 += 16) {
    float4 a0 = *(const float4*)(Ain + (size_t)(m0 + arow) * 384 + k0 + akq);
    float4 a1 = *(const float4*)(Ain + (size_t)(m0 + arow) * 384 + k0 + akq + 4);
    float4 b4 = *(const float4*)(Wp + (size_t)(k0 + lk) * 384 + n0 + ln4);
    __syncthreads();
    As[(akq + 0) * 132 + arow] = a0.x; As[(akq + 1) * 132 + arow] = a0.y;
    As[(akq + 2) * 132 + arow] = a0.z; As[(akq + 3) * 132 + arow] = a0.w;
    As[(akq + 4) * 132 + arow] = a1.x; As[(akq + 5) * 132 + arow] = a1.y;
    As[(akq + 6) * 132 + arow] = a1.z; As[(akq + 7) * 132 + arow] = a1.w;
    *(float4*)(Bs + lk * 64 + ln4) = b4;
    __syncthreads();
#pragma unroll
    for (int k = 0; k < 16; ++k) {
      float4 av0 = *(const float4*)(As + k * 132 + ty * 4);
      float4 av1 = *(const float4*)(As + k * 132 + 64 + ty * 4);
      float4 bv = *(const float4*)(Bs + k * 64 + tx * 4);
      float a0v[4] = {av0.x, av0.y, av0.z, av0.w};
      float a1v[4] = {av1.x, av1.y, av1.z, av1.w};
      float c[4] = {bv.x, bv.y, bv.z, bv.w};
#pragma unroll
      for (int i = 0; i < 4; ++i)
#pragma unroll
        for (int j = 0; j < 4; ++j) {
          accA[i][j] = fmaf(a0v[i], c[j], accA[i][j]);
          accB[i][j] = fmaf(a1v[i], c[j], accB[i][j]);
        }
    }
  }
  float bb[4];
  bb[0] = bp[n0 + tx * 4 + 0]; bb[1] = bp[n0 + tx * 4 + 1];
  bb[2] = bp[n0 + tx * 4 + 2]; bb[3] = bp[n0 + tx * 4 + 3];
#pragma unroll
  for (int i = 0; i < 4; ++i) {
    size_t rowA = (size_t)(m0 + ty * 4 + i);
    size_t rowB = (size_t)(m0 + 64 + ty * 4 + i);
    *(float4*)(Out + rowA * 384 + n0 + tx * 4) =
        make_float4(accA[i][0] + bb[0], accA[i][1] + bb[1], accA[i][2] + bb[2], accA[i][3] + bb[3]);
    *(float4*)(Out + rowB * 384 + n0 + tx * 4) =
        make_float4(accB[i][0] + bb[0], accB[i][1] + bb[1], accB[i][2] + bb[2], accB[i][3] + bb[3]);
  }
}

extern "C" void kernel_launch(void* const* d_in, const int* in_sizes, int n_in,
                              void* d_out, int out_size, void* d_ws, size_t ws_size,
                              hipStream_t stream) {
  (void)in_sizes; (void)n_in; (void)out_size; (void)ws_size;  // needs ~143 MB ws
  const float* q     = (const float*)d_in[0];
  const float* qpos  = (const float*)d_in[1];
  const float* Wq    = (const float*)d_in[2];
  const float* Wk    = (const float*)d_in[3];
  const float* Wv    = (const float*)d_in[4];
  const float* Wvoff = (const float*)d_in[5];
  const float* Woff1 = (const float*)d_in[6];
  const float* boff1 = (const float*)d_in[7];
  const float* lng   = (const float*)d_in[8];
  const float* lnb   = (const float*)d_in[9];
  const float* Woff2 = (const float*)d_in[10];
  const float* Wp    = (const float*)d_in[11];
  const float* bp    = (const float*)d_in[12];
  float* out = (float*)d_out;
  float* ws = (float*)d_ws;
  int*   idxb = (int*)(ws + OFF_IDX);
  float* sc   = ws + OFF_SC;
  float* qp   = ws + OFF_QP;
  float* voff = ws + OFF_VOFF;
  float* P    = ws + OFF_P;
  float* Q    = ws + OFF_Q;
  float* spos = ws + OFF_SP;
  float* w3   = ws + OFF_W3;
  int*   i3   = (int*)(ws + OFF_I3);
  float* qkh  = ws + OFF_QKH;
  float* VW   = ws + OFF_VW;
  float* opre = ws + OFF_OPRE;
  float* p3d  = ws + OFF_P3D;          // overlay on P (dead after offset_assemble)
  int*   p3i  = (int*)(ws + OFF_P3I);  // overlay on Q (dead after offset_assemble)

  knn_kernel<<<4096, 64, 0, stream>>>(qpos, idxb, sc);
  gemm_qp_voff<<<dim3(32, 6), 256, 0, stream>>>(q, Wq, Wvoff, qp, voff);
  gemm_pq3<<<dim3(64, 6, 3), 256, 0, stream>>>(voff, qp, q, Woff1, boff1, Wv, P, Q, VW);
  offset_assemble<<<8192, 256, 0, stream>>>(P, Q, idxb, lng, lnb, Woff2, qpos, sc, spos);
  three_nn_part<<<2048, 256, 0, stream>>>(spos, qpos, p3d, p3i);
  three_nn_merge<<<512, 256, 0, stream>>>(p3d, p3i, w3, i3);
  gemm_qkh<<<dim3(32, 6, 8), 256, 0, stream>>>(qp, Wk, qkh);
  attn_fuse2<<<4096, 256, 0, stream>>>(q, w3, i3, qkh, VW, opre);
  gemm_final<<<dim3(32, 6), 256, 0, stream>>>(opre, Wp, bp, out);
}

// Round 11
// 429.826 us; speedup vs baseline: 1.0389x; 1.0389x over previous
//
#include <hip/hip_runtime.h>
#include <math.h>

// improvedDeformableLocalCrossAttention — fp32, algebraically restructured:
//   h = shift_feat @ W_off1  ==  P[gathered point] + Q[query]
//   attn logits = interp . qkh   (kills the Wk GEMM)
//   out_pre = Sum_k attn * (Sum_gs w * VW[i])  where VW = q_gslice @ Wv_gslice
// R10: all remaining 64x64 GEMMs -> 128x64 tiles (8x4 accs).
// R11: offset_assemble: branchless A&S erf, single-pass mean/var, float2 loads.
// R12: three_nn 4-chunk split + exact merge (88.8 -> 74.6).
// R13: offset_assemble 4-rows/wave interleave (86 -> 66; total -41us).
// R14: FAILED: float2 candidate loads changed FP contraction -> selection flips.
// R15-R17: three_nn config sweep: all 2x-invariant => issue-bound.
// R18: three_nn insert via v_min/v_med3: 73.9 -> 65.5 (matched; issue-bound).
// R19: REGRESSED (66->70.6): 8-row widening cost occupancy; 4-row optimal.
// R20: offset_assemble XCD panel swizzle: FETCH 49.4->12.7MB (model confirmed),
//      dur 66->63.8 => now issue-floor (VALUBusy 92-98). Both leaders ~64us.
// R21: invisible middle tier (~300us across 7 kernels). Block-count audit:
//      gemm_qp_voff and gemm_final launch 192 blocks on 256 CUs (0.75/CU,
//      64 CUs idle, ~12% occupancy — same pathology as R12's three_nn).
//      (1) qp_voff -> grid z=2, one (W,O) pair per z: 384 blocks, accs halve.
//      (2) gemm_final -> 64x64 tiles: 384 blocks. Both keep each output
//      element's exact k0-then-k fmaf chain => bit-identical (R10 class).

#define ATTN_SCALE 0.14433756729740643f  // 48^-0.5

// ---- workspace layout (4-byte element offsets) ----
#define OFF_IDX   0u          // int   [4096*16]
#define OFF_SC    65536u      // float [4096*3]
#define OFF_QP    77824u      // float [4096*384]
#define OFF_VOFF  1650688u    // float [4096*384]
#define OFF_P     3223552u    // float [8192*384]   (dead after offset_assemble; 3nn part_d)
#define OFF_Q     6369280u    // float [8192*384]   (dead after offset_assemble; 3nn part_i)
#define OFF_SP    9515008u    // float [8*16384*3]
#define OFF_W3    9908224u    // float [8*16384*3]
#define OFF_I3    10301440u   // int   [8*16384*3]
#define OFF_QKH   10694656u   // float [4096*8*384]
#define OFF_VW    23277568u   // float [8192*384]
#define OFF_OPRE  35860480u   // float [4096*384]
// 3nn partials: 131072 queries * 8 chunks * 3 = 3145728 elems each (exact fit in P / Q)
#define OFF_P3D   OFF_P
#define OFF_P3I   OFF_Q

// Branchless erf, Abramowitz-Stegun 7.1.26 (|abs err| <= 1.5e-7):
//   erf(z) ~= sign(z) * (1 - (a1 t + ... + a5 t^5) exp(-z^2)), t = 1/(1+p|z|)
__device__ __forceinline__ float fast_erff(float z) {
  float az = fabsf(z);
  float d = fmaf(0.3275911f, az, 1.0f);
  float t0 = __builtin_amdgcn_rcpf(d);
  float t = t0 * fmaf(-d, t0, 2.0f);               // one Newton step
  float e = __builtin_amdgcn_exp2f(z * z * -1.4426950408889634f);
  float p = fmaf(fmaf(fmaf(fmaf(1.061405429f, t, -1.453152027f),
                           t, 1.421413741f),
                      t, -0.284496736f),
                 t, 0.254829592f);
  float r = 1.0f - p * t * e;
  return __builtin_copysignf(r, z);
}

// ---------------- kernel 1: kNN (K=16) + sc = 0.5*(max-min) of neighbor positions ----
__global__ __launch_bounds__(64) void knn_kernel(const float* __restrict__ qpos,
                                                 int* __restrict__ idx_out,
                                                 float* __restrict__ sc_out) {
  int bn = blockIdx.x;               // b*1024+n
  int b = bn >> 10, n = bn & 1023;
  int lane = threadIdx.x;
  const float* pb = qpos + (size_t)b * 1024 * 3;
  float qx = pb[n * 3 + 0], qy = pb[n * 3 + 1], qz = pb[n * 3 + 2];
  float qq = qx * qx + qy * qy + qz * qz;
  float d2[16];
#pragma unroll
  for (int u = 0; u < 16; ++u) {
    int p = lane + 64 * u;
    float px = pb[p * 3 + 0], py = pb[p * 3 + 1], pz = pb[p * 3 + 2];
    float pp = px * px + py * py + pz * pz;
    float dt = qx * px + qy * py + qz * pz;
    d2[u] = (qq + pp) - 2.0f * dt;   // mimic reference expansion form
  }
  float mnx = 3.4e38f, mny = 3.4e38f, mnz = 3.4e38f;
  float mxx = -3.4e38f, mxy = -3.4e38f, mxz = -3.4e38f;
  for (int r = 0; r < 16; ++r) {
    float best = d2[0]; int bu = 0;
#pragma unroll
    for (int u = 1; u < 16; ++u) { if (d2[u] < best) { best = d2[u]; bu = u; } }
    int bidx = lane + 64 * bu;
#pragma unroll
    for (int off = 32; off > 0; off >>= 1) {
      float ov = __shfl_xor(best, off);
      int oi = __shfl_xor(bidx, off);
      if (ov < best || (ov == best && oi < bidx)) { best = ov; bidx = oi; }
    }
    if ((bidx & 63) == lane) d2[bidx >> 6] = 3.4e38f;
    float wx = pb[bidx * 3 + 0], wy = pb[bidx * 3 + 1], wz = pb[bidx * 3 + 2];
    mnx = fminf(mnx, wx); mny = fminf(mny, wy); mnz = fminf(mnz, wz);
    mxx = fmaxf(mxx, wx); mxy = fmaxf(mxy, wy); mxz = fmaxf(mxz, wz);
    if (lane == 0) idx_out[bn * 16 + r] = bidx;
  }
  if (lane == 0) {
    sc_out[bn * 3 + 0] = 0.5f * (mxx - mnx);
    sc_out[bn * 3 + 1] = 0.5f * (mxy - mny);
    sc_out[bn * 3 + 2] = 0.5f * (mxz - mnz);
  }
}

// ---------------- kernel 2: qp/voff GEMM, 128x64 tile, z selects (W,O) pair ----------
// R21: was one fused kernel with 192 blocks (0.75/CU, 64 CUs idle). z-split
// doubles blocks to 384 and halves per-block accs. Each output element keeps
// the identical k0-then-k fmaf chain => bit-identical O1/O2.
__global__ __launch_bounds__(256) void gemm_qp_voff(const float* __restrict__ Aq,
    const float* __restrict__ W1, const float* __restrict__ W2,
    float* __restrict__ O1, float* __restrict__ O2) {
  __shared__ float As[16 * 132];
  __shared__ float Bs[16 * 64];
  int tid = threadIdx.x;
  int m0 = blockIdx.x * 128, n0 = blockIdx.y * 64;
  const float* W = blockIdx.z ? W2 : W1;
  float* O = blockIdx.z ? O2 : O1;
  int arow = tid >> 1, akq = (tid & 1) * 8;
  int lk = tid >> 4, ln4 = (tid & 15) * 4;
  int tx = tid & 15, ty = tid >> 4;
  float accA[4][4] = {{0.f}}, accB[4][4] = {{0.f}};
  for (int k0 = 0; k0 < 384; k0 += 16) {
    float4 a0 = *(const float4*)(Aq + (size_t)(m0 + arow) * 384 + k0 + akq);
    float4 a1 = *(const float4*)(Aq + (size_t)(m0 + arow) * 384 + k0 + akq + 4);
    float4 b4 = *(const float4*)(W + (size_t)(k0 + lk) * 384 + n0 + ln4);
    __syncthreads();
    As[(akq + 0) * 132 + arow] = a0.x; As[(akq + 1) * 132 + arow] = a0.y;
    As[(akq + 2) * 132 + arow] = a0.z; As[(akq + 3) * 132 + arow] = a0.w;
    As[(akq + 4) * 132 + arow] = a1.x; As[(akq + 5) * 132 + arow] = a1.y;
    As[(akq + 6) * 132 + arow] = a1.z; As[(akq + 7) * 132 + arow] = a1.w;
    *(float4*)(Bs + lk * 64 + ln4) = b4;
    __syncthreads();
#pragma unroll
    for (int k = 0; k < 16; ++k) {
      float4 av0 = *(const float4*)(As + k * 132 + ty * 4);
      float4 av1 = *(const float4*)(As + k * 132 + 64 + ty * 4);
      float4 bv = *(const float4*)(Bs + k * 64 + tx * 4);
      float x0[4] = {av0.x, av0.y, av0.z, av0.w};
      float x1[4] = {av1.x, av1.y, av1.z, av1.w};
      float c[4] = {bv.x, bv.y, bv.z, bv.w};
#pragma unroll
      for (int i = 0; i < 4; ++i)
#pragma unroll
        for (int j = 0; j < 4; ++j) {
          accA[i][j] = fmaf(x0[i], c[j], accA[i][j]);
          accB[i][j] = fmaf(x1[i], c[j], accB[i][j]);
        }
    }
  }
#pragma unroll
  for (int i = 0; i < 4; ++i) {
    size_t rA = (size_t)(m0 + ty * 4 + i);
    size_t rB = (size_t)(m0 + 64 + ty * 4 + i);
    *(float4*)(O + rA * 384 + n0 + tx * 4) = make_float4(accA[i][0], accA[i][1], accA[i][2], accA[i][3]);
    *(float4*)(O + rB * 384 + n0 + tx * 4) = make_float4(accB[i][0], accB[i][1], accB[i][2], accB[i][3]);
  }
}

// ---------------- kernel 3: 3-way K=192 group-sliced GEMM, 128x64 tile ---------------
__global__ __launch_bounds__(256) void gemm_pq3(const float* __restrict__ voff,
    const float* __restrict__ qp, const float* __restrict__ qin,
    const float* __restrict__ Woff1, const float* __restrict__ boff1,
    const float* __restrict__ Wv,
    float* __restrict__ P, float* __restrict__ Q, float* __restrict__ VW) {
  __shared__ float As[16 * 132];
  __shared__ float Bs[16 * 64];
  int tid = threadIdx.x;
  int m0 = blockIdx.x * 128, n0 = blockIdx.y * 64, z = blockIdx.z;
  int bg = m0 >> 10; int b = bg >> 1; int g = bg & 1; int ml0 = m0 & 1023;
  const float* Abase; const float* Bbase; const float* bias; float* Out; int bog;
  if (z == 0)      { Abase = voff; Bbase = Woff1;             bias = nullptr; Out = P;  bog = 0; }
  else if (z == 1) { Abase = qp;   Bbase = Woff1 + 192 * 384; bias = boff1;   Out = Q;  bog = 0; }
  else             { Abase = qin;  Bbase = Wv;                bias = nullptr; Out = VW; bog = 192 * 384; }
  const float* A = Abase + (size_t)b * 1024 * 384 + g * 192;
  const float* B = Bbase + (size_t)g * bog;
  int arow = tid >> 1, akq = (tid & 1) * 8;
  int lk = tid >> 4, ln4 = (tid & 15) * 4;
  int tx = tid & 15, ty = tid >> 4;
  float accA[4][4] = {{0.f}}, accB[4][4] = {{0.f}};
  for (int k0 = 0; k0 < 192; k0 += 16) {
    float4 a0 = *(const float4*)(A + (size_t)(ml0 + arow) * 384 + k0 + akq);
    float4 a1 = *(const float4*)(A + (size_t)(ml0 + arow) * 384 + k0 + akq + 4);
    float4 b4 = *(const float4*)(B + (size_t)(k0 + lk) * 384 + n0 + ln4);
    __syncthreads();
    As[(akq + 0) * 132 + arow] = a0.x; As[(akq + 1) * 132 + arow] = a0.y;
    As[(akq + 2) * 132 + arow] = a0.z; As[(akq + 3) * 132 + arow] = a0.w;
    As[(akq + 4) * 132 + arow] = a1.x; As[(akq + 5) * 132 + arow] = a1.y;
    As[(akq + 6) * 132 + arow] = a1.z; As[(akq + 7) * 132 + arow] = a1.w;
    *(float4*)(Bs + lk * 64 + ln4) = b4;
    __syncthreads();
#pragma unroll
    for (int k = 0; k < 16; ++k) {
      float4 av0 = *(const float4*)(As + k * 132 + ty * 4);
      float4 av1 = *(const float4*)(As + k * 132 + 64 + ty * 4);
      float4 bv = *(const float4*)(Bs + k * 64 + tx * 4);
      float a0v[4] = {av0.x, av0.y, av0.z, av0.w};
      float a1v[4] = {av1.x, av1.y, av1.z, av1.w};
      float c[4] = {bv.x, bv.y, bv.z, bv.w};
#pragma unroll
      for (int i = 0; i < 4; ++i)
#pragma unroll
        for (int j = 0; j < 4; ++j) {
          accA[i][j] = fmaf(a0v[i], c[j], accA[i][j]);
          accB[i][j] = fmaf(a1v[i], c[j], accB[i][j]);
        }
    }
  }
  float bb[4] = {0.f, 0.f, 0.f, 0.f};
  if (bias) {
    bb[0] = bias[n0 + tx * 4 + 0]; bb[1] = bias[n0 + tx * 4 + 1];
    bb[2] = bias[n0 + tx * 4 + 2]; bb[3] = bias[n0 + tx * 4 + 3];
  }
#pragma unroll
  for (int i = 0; i < 4; ++i) {
    size_t rowA = (size_t)(m0 + ty * 4 + i);
    size_t rowB = (size_t)(m0 + 64 + ty * 4 + i);
    *(float4*)(Out + rowA * 384 + n0 + tx * 4) =
        make_float4(accA[i][0] + bb[0], accA[i][1] + bb[1], accA[i][2] + bb[2], accA[i][3] + bb[3]);
    *(float4*)(Out + rowB * 384 + n0 + tx * 4) =
        make_float4(accB[i][0] + bb[0], accB[i][1] + bb[1], accB[i][2] + bb[2], accB[i][3] + bb[3]);
  }
}

// ---------------- kernel 4: h = P[idx]+Q -> LN -> GELU -> @W_off2 -> tanh -> shift ---
// R13 body (verbatim; 4 rows/wave, 256 threads) + R20 XCD swizzle: under
// round-robin dispatch, bn=(bid&7)*1024+(bid>>3) gives each XCD all blocks of
// one bg, whose P+Q panels (3MB) fit its 4MB L2. Index permutation only.
__global__ __launch_bounds__(256) void offset_assemble(const float* __restrict__ P,
    const float* __restrict__ Q, const int* __restrict__ idx,
    const float* __restrict__ lng, const float* __restrict__ lnb,
    const float* __restrict__ W2, const float* __restrict__ qpos,
    const float* __restrict__ sc, float* __restrict__ sp) {
  int bid = blockIdx.x;
  int bn = ((bid & 7) << 10) | (bid >> 3);   // bg*1024 + n  (8192 blocks)
  int wid = threadIdx.x >> 6, lane = threadIdx.x & 63;
  int n = bn & 1023, bg = bn >> 10, b = bg >> 1;
  int k0 = wid * 4;
  const int* idxr = idx + (((b << 10) + n) << 4) + k0;
  int mi[4];
#pragma unroll
  for (int r = 0; r < 4; ++r) mi[r] = idxr[r];
  const float* Qr = Q + ((size_t)bg * 1024 + n) * 384;
  const float* Pr[4];
#pragma unroll
  for (int r = 0; r < 4; ++r) Pr[r] = P + ((size_t)bg * 1024 + mi[r]) * 384;

  float h[4][6];
  float s[4] = {0.f, 0.f, 0.f, 0.f}, s2[4] = {0.f, 0.f, 0.f, 0.f};
#pragma unroll
  for (int u = 0; u < 3; ++u) {
    int c = 2 * lane + 128 * u;
    float2 qv = *(const float2*)(Qr + c);
#pragma unroll
    for (int r = 0; r < 4; ++r) {
      float2 pv = *(const float2*)(Pr[r] + c);
      float h0 = pv.x + qv.x, h1 = pv.y + qv.y;
      h[r][2 * u] = h0; h[r][2 * u + 1] = h1;
      s[r] += h0 + h1;
      s2[r] = fmaf(h0, h0, s2[r]);
      s2[r] = fmaf(h1, h1, s2[r]);
    }
  }
#pragma unroll
  for (int off = 32; off > 0; off >>= 1) {  // 8 interleaved butterflies
#pragma unroll
    for (int r = 0; r < 4; ++r) {
      s[r]  += __shfl_xor(s[r], off);
      s2[r] += __shfl_xor(s2[r], off);
    }
  }
  float mu[4], rstd[4];
#pragma unroll
  for (int r = 0; r < 4; ++r) {
    mu[r] = s[r] * (1.0f / 384.0f);
    float var = s2[r] * (1.0f / 384.0f) - mu[r] * mu[r];
    rstd[r] = 1.0f / sqrtf(var + 1e-5f);
  }
  float o0[4] = {0.f, 0.f, 0.f, 0.f}, o1[4] = {0.f, 0.f, 0.f, 0.f}, o2[4] = {0.f, 0.f, 0.f, 0.f};
#pragma unroll
  for (int u = 0; u < 3; ++u) {
    int c = 2 * lane + 128 * u;
    float2 gv  = *(const float2*)(lng + c);
    float2 bv  = *(const float2*)(lnb + c);
    float2 w01 = *(const float2*)(W2 + (size_t)c * 3);      // [c][0],[c][1]
    float2 w23 = *(const float2*)(W2 + (size_t)c * 3 + 2);  // [c][2],[c+1][0]
    float2 w45 = *(const float2*)(W2 + (size_t)c * 3 + 4);  // [c+1][1],[c+1][2]
#pragma unroll
    for (int r = 0; r < 4; ++r) {
      float x0 = fmaf((h[r][2 * u] - mu[r]) * rstd[r], gv.x, bv.x);
      float x1 = fmaf((h[r][2 * u + 1] - mu[r]) * rstd[r], gv.y, bv.y);
      float g0 = x0 * fmaf(fast_erff(x0 * 0.70710678118654752f), 0.5f, 0.5f);
      float g1 = x1 * fmaf(fast_erff(x1 * 0.70710678118654752f), 0.5f, 0.5f);
      o0[r] = fmaf(g0, w01.x, o0[r]); o1[r] = fmaf(g0, w01.y, o1[r]); o2[r] = fmaf(g0, w23.x, o2[r]);
      o0[r] = fmaf(g1, w23.y, o0[r]); o1[r] = fmaf(g1, w45.x, o1[r]); o2[r] = fmaf(g1, w45.y, o2[r]);
    }
  }
#pragma unroll
  for (int off = 32; off > 0; off >>= 1) {  // 12 interleaved butterflies
#pragma unroll
    for (int r = 0; r < 4; ++r) {
      o0[r] += __shfl_xor(o0[r], off);
      o1[r] += __shfl_xor(o1[r], off);
      o2[r] += __shfl_xor(o2[r], off);
    }
  }
  if (lane < 3) {
    float scv = sc[(((b << 10) + n)) * 3 + lane];
#pragma unroll
    for (int r = 0; r < 4; ++r) {
      float o = (lane == 0) ? o0[r] : ((lane == 1) ? o1[r] : o2[r]);
      float off = tanhf(o);
      float p = qpos[((size_t)b * 1024 + mi[r]) * 3 + lane];
      int row = (bn << 4) + k0 + r;       // (bg*1024+n)*16+k
      sp[(size_t)row * 3 + lane] = p + off * scv;
    }
  }
}

// ---------------- kernel 5a: three_nn partial — 8 chunks of 128, 2 chains, 2048 blks -
// R18: value-half of the sorted-triple insert via v_min/v_med3 (bitwise-exact
// selection); index compares verbatim strict-<. Distance exprs and candidate
// load shape untouched (R14 lesson). Geometry frozen at R17.
__global__ __launch_bounds__(256) void three_nn_part(const float* __restrict__ spos,
    const float* __restrict__ qpos, float* __restrict__ part_d, int* __restrict__ part_i) {
  __shared__ float px[128], py[128], pz[128], pp[128];
  int bid = blockIdx.x;             // bg(3b) | qg(5b) | chunk(3b)
  int bg = bid >> 8;
  int qg = (bid >> 3) & 31;
  int c  = bid & 7;
  int b = bg >> 1;
  int j0 = c << 7;
  const float* pb = qpos + (size_t)b * 1024 * 3;
  int tid = threadIdx.x;
  if (tid < 128) {
    int j = j0 + tid;
    float x = pb[j * 3 + 0], y = pb[j * 3 + 1], z = pb[j * 3 + 2];
    px[tid] = x; py[tid] = y; pz[tid] = z; pp[tid] = x * x + y * y + z * z;
  }
  __syncthreads();
  int m0 = qg * 512;
  int mA = m0 + tid;
  int mB = mA + 256;
  const float* spA = spos + ((size_t)bg * 16384 + mA) * 3;
  const float* spB = spos + ((size_t)bg * 16384 + mB) * 3;
  float sxA = spA[0], syA = spA[1], szA = spA[2];
  float sxB = spB[0], syB = spB[1], szB = spB[2];
  float qqA = sxA * sxA + syA * syA + szA * szA;
  float qqB = sxB * sxB + syB * syB + szB * szB;
  float d0A = 3.4e38f, d1A = 3.4e38f, d2A = 3.4e38f; int i0A = 0, i1A = 0, i2A = 0;
  float d0B = 3.4e38f, d1B = 3.4e38f, d2B = 3.4e38f; int i0B = 0, i1B = 0, i2B = 0;
#pragma unroll 8
  for (int jj = 0; jj < 128; ++jj) {
    int j = j0 + jj;
    float cx = px[jj], cy = py[jj], cz = pz[jj], cw = pp[jj];
    float dtA = sxA * cx + syA * cy + szA * cz;
    float dA = (qqA + cw) - 2.0f * dtA;
    float dtB = sxB * cx + syB * cy + szB * cz;
    float dB = (qqB + cw) - 2.0f * dtB;
    {
      bool c0 = dA < d0A, c1 = dA < d1A, c2 = dA < d2A;
      int   ni2 = c1 ? i1A : (c2 ? j : i2A);
      int   ni1 = c0 ? i0A : (c1 ? j : i1A);
      float nd2 = __builtin_amdgcn_fmed3f(d1A, d2A, dA);  // == c1?d1:(c2?dA:d2)
      float nd1 = __builtin_amdgcn_fmed3f(d0A, d1A, dA);  // == c0?d0:(c1?dA:d1)
      d0A = fminf(d0A, dA);  i0A = c0 ? j : i0A;
      d1A = nd1; i1A = ni1; d2A = nd2; i2A = ni2;
    }
    {
      bool c0 = dB < d0B, c1 = dB < d1B, c2 = dB < d2B;
      int   ni2 = c1 ? i1B : (c2 ? j : i2B);
      int   ni1 = c0 ? i0B : (c1 ? j : i1B);
      float nd2 = __builtin_amdgcn_fmed3f(d1B, d2B, dB);
      float nd1 = __builtin_amdgcn_fmed3f(d0B, d1B, dB);
      d0B = fminf(d0B, dB);  i0B = c0 ? j : i0B;
      d1B = nd1; i1B = ni1; d2B = nd2; i2B = ni2;
    }
  }
  {
    size_t base = (((size_t)bg * 8 + c) * 16384 + mA) * 3;
    part_d[base + 0] = d0A; part_d[base + 1] = d1A; part_d[base + 2] = d2A;
    part_i[base + 0] = i0A; part_i[base + 1] = i1A; part_i[base + 2] = i2A;
  }
  {
    size_t base = (((size_t)bg * 8 + c) * 16384 + mB) * 3;
    part_d[base + 0] = d0B; part_d[base + 1] = d1B; part_d[base + 2] = d2B;
    part_i[base + 0] = i0B; part_i[base + 1] = i1B; part_i[base + 2] = i2B;
  }
}

// ---------------- kernel 5b: three_nn merge — insert 8 chunk triples in order --------
// Inserting each chunk's sorted triple (chunk order, then slot order) with strict-<
// and incumbent-wins reproduces the sequential scan's (d, scan-position) ordering
// exactly. Epilogue expressions verbatim from the old kernel.
__global__ __launch_bounds__(256) void three_nn_merge(const float* __restrict__ part_d,
    const int* __restrict__ part_i, float* __restrict__ w3, int* __restrict__ i3) {
  int q = blockIdx.x * 256 + threadIdx.x;   // 0..131071: bg*16384+m
  int bg = q >> 14, m = q & 16383;
  size_t pb = (((size_t)bg * 8) * 16384 + m) * 3;
  float D0 = part_d[pb + 0], D1 = part_d[pb + 1], D2 = part_d[pb + 2];
  int   I0 = part_i[pb + 0], I1 = part_i[pb + 1], I2 = part_i[pb + 2];
#pragma unroll
  for (int c = 1; c < 8; ++c) {
    size_t base = (((size_t)bg * 8 + c) * 16384 + m) * 3;
#pragma unroll
    for (int s = 0; s < 3; ++s) {
      float dv = part_d[base + s];
      int   iv = part_i[base + s];
      bool c0 = dv < D0, c1 = dv < D1, c2 = dv < D2;
      float nd2 = c1 ? D1 : (c2 ? dv : D2);
      int   ni2 = c1 ? I1 : (c2 ? iv : I2);
      float nd1 = c0 ? D0 : (c1 ? dv : D1);
      int   ni1 = c0 ? I0 : (c1 ? iv : I1);
      D0 = c0 ? dv : D0;  I0 = c0 ? iv : I0;
      D1 = nd1; I1 = ni1; D2 = nd2; I2 = ni2;
    }
  }
  float t0 = sqrtf(fmaxf(D0, 0.f)), t1 = sqrtf(fmaxf(D1, 0.f)), t2 = sqrtf(fmaxf(D2, 0.f));
  float r0 = 1.0f / (t0 + 1e-8f), r1 = 1.0f / (t1 + 1e-8f), r2 = 1.0f / (t2 + 1e-8f);
  float inv = 1.0f / (r0 + r1 + r2);
  size_t base = ((size_t)bg * 16384 + m) * 3;
  w3[base + 0] = r0 * inv; w3[base + 1] = r1 * inv; w3[base + 2] = r2 * inv;
  i3[base + 0] = I0; i3[base + 1] = I1; i3[base + 2] = I2;
}

// ---------------- kernel 6: qkh GEMM, 128x64 tile (K=48 per head) --------------------
__global__ __launch_bounds__(256) void gemm_qkh(const float* __restrict__ qp,
    const float* __restrict__ Wk, float* __restrict__ qkh) {
  __shared__ float As[16 * 132];
  __shared__ float Bs[16 * 68];
  int tid = threadIdx.x;
  int m0 = blockIdx.x * 128, c0 = blockIdx.y * 64, h = blockIdx.z;
  int arow = tid >> 1, akq = (tid & 1) * 8;
  int lm = tid >> 2, lq = (tid & 3) * 4;
  int tx = tid & 15, ty = tid >> 4;
  float accA[4][4] = {{0.f}}, accB[4][4] = {{0.f}};
  for (int k0 = 0; k0 < 48; k0 += 16) {
    float4 a0 = *(const float4*)(qp + (size_t)(m0 + arow) * 384 + h * 48 + k0 + akq);
    float4 a1 = *(const float4*)(qp + (size_t)(m0 + arow) * 384 + h * 48 + k0 + akq + 4);
    float4 b4 = *(const float4*)(Wk + (size_t)(c0 + lm) * 384 + h * 48 + k0 + lq);
    __syncthreads();
    As[(akq + 0) * 132 + arow] = a0.x; As[(akq + 1) * 132 + arow] = a0.y;
    As[(akq + 2) * 132 + arow] = a0.z; As[(akq + 3) * 132 + arow] = a0.w;
    As[(akq + 4) * 132 + arow] = a1.x; As[(akq + 5) * 132 + arow] = a1.y;
    As[(akq + 6) * 132 + arow] = a1.z; As[(akq + 7) * 132 + arow] = a1.w;
    Bs[(lq + 0) * 68 + lm] = b4.x; Bs[(lq + 1) * 68 + lm] = b4.y;
    Bs[(lq + 2) * 68 + lm] = b4.z; Bs[(lq + 3) * 68 + lm] = b4.w;
    __syncthreads();
#pragma unroll
    for (int k = 0; k < 16; ++k) {
      float4 av0 = *(const float4*)(As + k * 132 + ty * 4);
      float4 av1 = *(const float4*)(As + k * 132 + 64 + ty * 4);
      float4 bv = *(const float4*)(Bs + k * 68 + tx * 4);
      float a0v[4] = {av0.x, av0.y, av0.z, av0.w};
      float a1v[4] = {av1.x, av1.y, av1.z, av1.w};
      float c[4] = {bv.x, bv.y, bv.z, bv.w};
#pragma unroll
      for (int i = 0; i < 4; ++i)
#pragma unroll
        for (int j = 0; j < 4; ++j) {
          accA[i][j] = fmaf(a0v[i], c[j], accA[i][j]);
          accB[i][j] = fmaf(a1v[i], c[j], accB[i][j]);
        }
    }
  }
#pragma unroll
  for (int i = 0; i < 4; ++i) {
    size_t rowA = (size_t)(m0 + ty * 4 + i);
    size_t rowB = (size_t)(m0 + 64 + ty * 4 + i);
    *(float4*)(qkh + (rowA * 8 + h) * 384 + c0 + tx * 4) =
        make_float4(accA[i][0], accA[i][1], accA[i][2], accA[i][3]);
    *(float4*)(qkh + (rowB * 8 + h) * 384 + c0 + tx * 4) =
        make_float4(accB[i][0], accB[i][1], accB[i][2], accB[i][3]);
  }
}

// ---------------- kernel 7: fused interp + logits + softmax + out_pre ----------------
__global__ __launch_bounds__(256) void attn_fuse2(const float* __restrict__ v,
    const float* __restrict__ w3, const int* __restrict__ i3,
    const float* __restrict__ qkh, const float* __restrict__ VW,
    float* __restrict__ opre) {
  __shared__ float A[16 * 388];      // interp rows [k][c]
  __shared__ float Bv[16 * 388];     // interpVW rows [k][c']
  __shared__ float wk[16][2][3];
  __shared__ int ik[16][2][3];
  __shared__ float attnw[8 * 16];
  __shared__ float lpart[2][128];
  int tid = threadIdx.x;
  // XCD-aware swizzle: batch b -> XCD pair {2b, 2b+1} (round-robin dispatch assumed)
  int blk = blockIdx.x;
  int b = (blk & 7) >> 1;
  int n = ((blk & 1) << 9) | (blk >> 3);
  int bn = (b << 10) | n;
  if (tid < 96) {
    int k = tid / 6; int rem = tid % 6; int g = rem / 3; int s = rem % 3;
    size_t base = ((size_t)(b * 2 + g) * 16384 + n * 16 + k) * 3 + s;
    wk[k][g][s] = w3[base];
    ik[k][g][s] = i3[base];
  }
  __syncthreads();
  {  // build interp rows A[k][c] and interpVW rows Bv[k][c']; chunks c=(tid&15)*4+64u
    int r = tid >> 4;
    int cL = (tid & 15) * 4;
    const float* vr[2][3]; const float* wr[2][3];
#pragma unroll
    for (int g = 0; g < 2; ++g)
#pragma unroll
      for (int s = 0; s < 3; ++s) {
        vr[g][s] = v + ((size_t)b * 1024 + ik[r][g][s]) * 384;
        wr[g][s] = VW + ((size_t)(b * 2 + g) * 1024 + ik[r][g][s]) * 384;
      }
    float u0 = wk[r][0][0], u1 = wk[r][0][1], u2 = wk[r][0][2];
    float y0 = wk[r][1][0], y1 = wk[r][1][1], y2 = wk[r][1][2];
#pragma unroll
    for (int u = 0; u < 6; ++u) {
      int c = cL + 64 * u;
      int g = (u >= 3) ? 1 : 0;
      float w0 = wk[r][g][0], w1 = wk[r][g][1], w2 = wk[r][g][2];
      float4 f0 = *(const float4*)(vr[g][0] + c);
      float4 f1 = *(const float4*)(vr[g][1] + c);
      float4 f2 = *(const float4*)(vr[g][2] + c);
      float4 o;
      o.x = w0 * f0.x + w1 * f1.x + w2 * f2.x;
      o.y = w0 * f0.y + w1 * f1.y + w2 * f2.y;
      o.z = w0 * f0.z + w1 * f1.z + w2 * f2.z;
      o.w = w0 * f0.w + w1 * f1.w + w2 * f2.w;
      *(float4*)(A + r * 388 + c) = o;
      float4 a0 = *(const float4*)(wr[0][0] + c);
      float4 a1 = *(const float4*)(wr[0][1] + c);
      float4 a2 = *(const float4*)(wr[0][2] + c);
      float4 b0 = *(const float4*)(wr[1][0] + c);
      float4 b1 = *(const float4*)(wr[1][1] + c);
      float4 b2 = *(const float4*)(wr[1][2] + c);
      float4 p;
      p.x = u0 * a0.x + u1 * a1.x + u2 * a2.x + y0 * b0.x + y1 * b1.x + y2 * b2.x;
      p.y = u0 * a0.y + u1 * a1.y + u2 * a2.y + y0 * b0.y + y1 * b1.y + y2 * b2.y;
      p.z = u0 * a0.z + u1 * a1.z + u2 * a2.z + y0 * b0.z + y1 * b1.z + y2 * b2.z;
      p.w = u0 * a0.w + u1 * a1.w + u2 * a2.w + y0 * b0.w + y1 * b1.w + y2 * b2.w;
      *(float4*)(Bv + r * 388 + c) = p;
    }
  }
  __syncthreads();
  {  // logits with all 256 threads: (k,h,half) half-dots, then combine
    int r = tid & 15, h = (tid >> 4) & 7, half = tid >> 7;
    const float* qr = qkh + ((size_t)bn * 8 + h) * 384 + half * 192;
    const float* ar = A + r * 388 + half * 192;
    float acc = 0.f;
    for (int c = 0; c < 192; c += 4) {
      float4 av = *(const float4*)(ar + c);
      float4 qv = *(const float4*)(qr + c);
      acc += av.x * qv.x + av.y * qv.y + av.z * qv.z + av.w * qv.w;
    }
    lpart[half][h * 16 + r] = acc;
  }
  __syncthreads();
  if (tid < 128) attnw[tid] = (lpart[0][tid] + lpart[1][tid]) * ATTN_SCALE;
  __syncthreads();
  if (tid < 8) {  // softmax over k
    int h = tid;
    float m = -3.4e38f;
    for (int k = 0; k < 16; ++k) m = fmaxf(m, attnw[h * 16 + k]);
    float s = 0.f;
    for (int k = 0; k < 16; ++k) { float e = expf(attnw[h * 16 + k] - m); attnw[h * 16 + k] = e; s += e; }
    float inv = 1.0f / s;
    for (int k = 0; k < 16; ++k) attnw[h * 16 + k] *= inv;
  }
  __syncthreads();
  {  // out_pre[c'] = sum_k attn[h(c'),k] * Bv[k][c']
#pragma unroll
    for (int u = 0; u < 2; ++u) {
      int c = tid + 256 * u;
      if (c < 384) {
        int h = c / 48;
        float s = 0.f;
#pragma unroll
        for (int k = 0; k < 16; ++k) s = fmaf(attnw[h * 16 + k], Bv[k * 388 + c], s);
        opre[(size_t)bn * 384 + c] = s;
      }
    }
  }
}

// ---------------- kernel 9: out = out_pre @ Wp + bp, 64x64 tile ----------------------
// R21: 64x64 tiles (was 128x64 @ 192 blocks = 0.75/CU). 384 blocks; each
// output element's k0-then-k fmaf chain unchanged => bit-identical.
__global__ __launch_bounds__(256) void gemm_final(const float* __restrict__ Ain,
    const float* __restrict__ Wp, const float* __restrict__ bp,
    float* __restrict__ Out) {
  __shared__ float As[16 * 68];
  __shared__ float Bs[16 * 64];
  int tid = threadIdx.x;
  int m0 = blockIdx.x * 64, n0 = blockIdx.y * 64;
  int arow = tid >> 2, akq = (tid & 3) * 4;
  int lk = tid >> 4, ln4 = (tid & 15) * 4;
  int tx = tid & 15, ty = tid >> 4;
  float acc[4][4] = {{0.f}};
  for (int k0 = 0; k0 < 384; k0 += 16) {
    float4 a0 = *(const float4*)(Ain + (size_t)(m0 + arow) * 384 + k0 + akq);
    float4 b4 = *(const float4*)(Wp + (size_t)(k0 + lk) * 384 + n0 + ln4);
    __syncthreads();
    As[(akq + 0) * 68 + arow] = a0.x; As[(akq + 1) * 68 + arow] = a0.y;
    As[(akq + 2) * 68 + arow] = a0.z; As[(akq + 3) * 68 + arow] = a0.w;
    *(float4*)(Bs + lk * 64 + ln4) = b4;
    __syncthreads();
#pragma unroll
    for (int k = 0; k < 16; ++k) {
      float4 av = *(const float4*)(As + k * 68 + ty * 4);
      float4 bv = *(const float4*)(Bs + k * 64 + tx * 4);
      float a0v[4] = {av.x, av.y, av.z, av.w};
      float c[4] = {bv.x, bv.y, bv.z, bv.w};
#pragma unroll
      for (int i = 0; i < 4; ++i)
#pragma unroll
        for (int j = 0; j < 4; ++j) {
          acc[i][j] = fmaf(a0v[i], c[j], acc[i][j]);
        }
    }
  }
  float bb[4];
  bb[0] = bp[n0 + tx * 4 + 0]; bb[1] = bp[n0 + tx * 4 + 1];
  bb[2] = bp[n0 + tx * 4 + 2]; bb[3] = bp[n0 + tx * 4 + 3];
#pragma unroll
  for (int i = 0; i < 4; ++i) {
    size_t row = (size_t)(m0 + ty * 4 + i);
    *(float4*)(Out + row * 384 + n0 + tx * 4) =
        make_float4(acc[i][0] + bb[0], acc[i][1] + bb[1], acc[i][2] + bb[2], acc[i][3] + bb[3]);
  }
}

extern "C" void kernel_launch(void* const* d_in, const int* in_sizes, int n_in,
                              void* d_out, int out_size, void* d_ws, size_t ws_size,
                              hipStream_t stream) {
  (void)in_sizes; (void)n_in; (void)out_size; (void)ws_size;  // needs ~143 MB ws
  const float* q     = (const float*)d_in[0];
  const float* qpos  = (const float*)d_in[1];
  const float* Wq    = (const float*)d_in[2];
  const float* Wk    = (const float*)d_in[3];
  const float* Wv    = (const float*)d_in[4];
  const float* Wvoff = (const float*)d_in[5];
  const float* Woff1 = (const float*)d_in[6];
  const float* boff1 = (const float*)d_in[7];
  const float* lng   = (const float*)d_in[8];
  const float* lnb   = (const float*)d_in[9];
  const float* Woff2 = (const float*)d_in[10];
  const float* Wp    = (const float*)d_in[11];
  const float* bp    = (const float*)d_in[12];
  float* out = (float*)d_out;
  float* ws = (float*)d_ws;
  int*   idxb = (int*)(ws + OFF_IDX);
  float* sc   = ws + OFF_SC;
  float* qp   = ws + OFF_QP;
  float* voff = ws + OFF_VOFF;
  float* P    = ws + OFF_P;
  float* Q    = ws + OFF_Q;
  float* spos = ws + OFF_SP;
  float* w3   = ws + OFF_W3;
  int*   i3   = (int*)(ws + OFF_I3);
  float* qkh  = ws + OFF_QKH;
  float* VW   = ws + OFF_VW;
  float* opre = ws + OFF_OPRE;
  float* p3d  = ws + OFF_P3D;          // overlay on P (dead after offset_assemble)
  int*   p3i  = (int*)(ws + OFF_P3I);  // overlay on Q (dead after offset_assemble)

  knn_kernel<<<4096, 64, 0, stream>>>(qpos, idxb, sc);
  gemm_qp_voff<<<dim3(32, 6, 2), 256, 0, stream>>>(q, Wq, Wvoff, qp, voff);
  gemm_pq3<<<dim3(64, 6, 3), 256, 0, stream>>>(voff, qp, q, Woff1, boff1, Wv, P, Q, VW);
  offset_assemble<<<8192, 256, 0, stream>>>(P, Q, idxb, lng, lnb, Woff2, qpos, sc, spos);
  three_nn_part<<<2048, 256, 0, stream>>>(spos, qpos, p3d, p3i);
  three_nn_merge<<<512, 256, 0, stream>>>(p3d, p3i, w3, i3);
  gemm_qkh<<<dim3(32, 6, 8), 256, 0, stream>>>(qp, Wk, qkh);
  attn_fuse2<<<4096, 256, 0, stream>>>(q, w3, i3, qkh, VW, opre);
  gemm_final<<<dim3(64, 6), 256, 0, stream>>>(opre, Wp, bp, out);
}

// Round 12
// 415.289 us; speedup vs baseline: 1.0752x; 1.0350x over previous
//
#include <hip/hip_runtime.h>
#include <math.h>

// improvedDeformableLocalCrossAttention — fp32, algebraically restructured:
//   h = shift_feat @ W_off1  ==  P[gathered point] + Q[query]
//   attn logits = interp . qkh   (kills the Wk GEMM)
//   out_pre = Sum_k attn * (Sum_gs w * VW[i])  where VW = q_gslice @ Wv_gslice
// R10: 64x64 GEMMs -> 128x64 tiles (bit-identical per-element k-chains).
// R11: offset_assemble: branchless A&S erf, single-pass mean/var, float2 loads.
// R12: three_nn 4-chunk split + exact merge (88.8 -> 74.6).
// R13: offset_assemble 4-rows/wave interleave (86 -> 66).
// R14: FAILED: float2 candidate loads changed FP contraction -> selection flips.
// R15-R17: three_nn config sweep: all 2x-invariant => issue-bound.
// R18: three_nn insert via v_min/v_med3: 73.9 -> 65.5 (matched).
// R19: REGRESSED: 8-row widening cost occupancy; 4-row optimal.
// R20: offset_assemble XCD panel swizzle: FETCH 49.4->12.7MB, 66->63.8.
// R21: gemm_qp_voff z-split + gemm_final 64x64 (192->384 blocks each).
//      Leaders stable at 63.6+63.6, both at bit-exact issue floors.
// R22: gemm_pq3 (est ~55us by FLOP count, just under top-5 cutoff) 128x64 ->
//      128x128 tile: per k-step 64 fma / 4 ds_read_b128 (was 32/3), barriers
//      amortize 2x, staging per FLOP halves. Same R10 class: every output
//      element keeps its exact k0-then-k fmaf chain => bit-identical.

#define ATTN_SCALE 0.14433756729740643f  // 48^-0.5

// ---- workspace layout (4-byte element offsets) ----
#define OFF_IDX   0u          // int   [4096*16]
#define OFF_SC    65536u      // float [4096*3]
#define OFF_QP    77824u      // float [4096*384]
#define OFF_VOFF  1650688u    // float [4096*384]
#define OFF_P     3223552u    // float [8192*384]   (dead after offset_assemble; 3nn part_d)
#define OFF_Q     6369280u    // float [8192*384]   (dead after offset_assemble; 3nn part_i)
#define OFF_SP    9515008u    // float [8*16384*3]
#define OFF_W3    9908224u    // float [8*16384*3]
#define OFF_I3    10301440u   // int   [8*16384*3]
#define OFF_QKH   10694656u   // float [4096*8*384]
#define OFF_VW    23277568u   // float [8192*384]
#define OFF_OPRE  35860480u   // float [4096*384]
// 3nn partials: 131072 queries * 8 chunks * 3 = 3145728 elems each (exact fit in P / Q)
#define OFF_P3D   OFF_P
#define OFF_P3I   OFF_Q

// Branchless erf, Abramowitz-Stegun 7.1.26 (|abs err| <= 1.5e-7):
//   erf(z) ~= sign(z) * (1 - (a1 t + ... + a5 t^5) exp(-z^2)), t = 1/(1+p|z|)
__device__ __forceinline__ float fast_erff(float z) {
  float az = fabsf(z);
  float d = fmaf(0.3275911f, az, 1.0f);
  float t0 = __builtin_amdgcn_rcpf(d);
  float t = t0 * fmaf(-d, t0, 2.0f);               // one Newton step
  float e = __builtin_amdgcn_exp2f(z * z * -1.4426950408889634f);
  float p = fmaf(fmaf(fmaf(fmaf(1.061405429f, t, -1.453152027f),
                           t, 1.421413741f),
                      t, -0.284496736f),
                 t, 0.254829592f);
  float r = 1.0f - p * t * e;
  return __builtin_copysignf(r, z);
}

// ---------------- kernel 1: kNN (K=16) + sc = 0.5*(max-min) of neighbor positions ----
__global__ __launch_bounds__(64) void knn_kernel(const float* __restrict__ qpos,
                                                 int* __restrict__ idx_out,
                                                 float* __restrict__ sc_out) {
  int bn = blockIdx.x;               // b*1024+n
  int b = bn >> 10, n = bn & 1023;
  int lane = threadIdx.x;
  const float* pb = qpos + (size_t)b * 1024 * 3;
  float qx = pb[n * 3 + 0], qy = pb[n * 3 + 1], qz = pb[n * 3 + 2];
  float qq = qx * qx + qy * qy + qz * qz;
  float d2[16];
#pragma unroll
  for (int u = 0; u < 16; ++u) {
    int p = lane + 64 * u;
    float px = pb[p * 3 + 0], py = pb[p * 3 + 1], pz = pb[p * 3 + 2];
    float pp = px * px + py * py + pz * pz;
    float dt = qx * px + qy * py + qz * pz;
    d2[u] = (qq + pp) - 2.0f * dt;   // mimic reference expansion form
  }
  float mnx = 3.4e38f, mny = 3.4e38f, mnz = 3.4e38f;
  float mxx = -3.4e38f, mxy = -3.4e38f, mxz = -3.4e38f;
  for (int r = 0; r < 16; ++r) {
    float best = d2[0]; int bu = 0;
#pragma unroll
    for (int u = 1; u < 16; ++u) { if (d2[u] < best) { best = d2[u]; bu = u; } }
    int bidx = lane + 64 * bu;
#pragma unroll
    for (int off = 32; off > 0; off >>= 1) {
      float ov = __shfl_xor(best, off);
      int oi = __shfl_xor(bidx, off);
      if (ov < best || (ov == best && oi < bidx)) { best = ov; bidx = oi; }
    }
    if ((bidx & 63) == lane) d2[bidx >> 6] = 3.4e38f;
    float wx = pb[bidx * 3 + 0], wy = pb[bidx * 3 + 1], wz = pb[bidx * 3 + 2];
    mnx = fminf(mnx, wx); mny = fminf(mny, wy); mnz = fminf(mnz, wz);
    mxx = fmaxf(mxx, wx); mxy = fmaxf(mxy, wy); mxz = fmaxf(mxz, wz);
    if (lane == 0) idx_out[bn * 16 + r] = bidx;
  }
  if (lane == 0) {
    sc_out[bn * 3 + 0] = 0.5f * (mxx - mnx);
    sc_out[bn * 3 + 1] = 0.5f * (mxy - mny);
    sc_out[bn * 3 + 2] = 0.5f * (mxz - mnz);
  }
}

// ---------------- kernel 2: qp/voff GEMM, 128x64 tile, z selects (W,O) pair ----------
// R21: z-split doubles blocks to 384. Each output element keeps the identical
// k0-then-k fmaf chain => bit-identical O1/O2.
__global__ __launch_bounds__(256) void gemm_qp_voff(const float* __restrict__ Aq,
    const float* __restrict__ W1, const float* __restrict__ W2,
    float* __restrict__ O1, float* __restrict__ O2) {
  __shared__ float As[16 * 132];
  __shared__ float Bs[16 * 64];
  int tid = threadIdx.x;
  int m0 = blockIdx.x * 128, n0 = blockIdx.y * 64;
  const float* W = blockIdx.z ? W2 : W1;
  float* O = blockIdx.z ? O2 : O1;
  int arow = tid >> 1, akq = (tid & 1) * 8;
  int lk = tid >> 4, ln4 = (tid & 15) * 4;
  int tx = tid & 15, ty = tid >> 4;
  float accA[4][4] = {{0.f}}, accB[4][4] = {{0.f}};
  for (int k0 = 0; k0 < 384; k0 += 16) {
    float4 a0 = *(const float4*)(Aq + (size_t)(m0 + arow) * 384 + k0 + akq);
    float4 a1 = *(const float4*)(Aq + (size_t)(m0 + arow) * 384 + k0 + akq + 4);
    float4 b4 = *(const float4*)(W + (size_t)(k0 + lk) * 384 + n0 + ln4);
    __syncthreads();
    As[(akq + 0) * 132 + arow] = a0.x; As[(akq + 1) * 132 + arow] = a0.y;
    As[(akq + 2) * 132 + arow] = a0.z; As[(akq + 3) * 132 + arow] = a0.w;
    As[(akq + 4) * 132 + arow] = a1.x; As[(akq + 5) * 132 + arow] = a1.y;
    As[(akq + 6) * 132 + arow] = a1.z; As[(akq + 7) * 132 + arow] = a1.w;
    *(float4*)(Bs + lk * 64 + ln4) = b4;
    __syncthreads();
#pragma unroll
    for (int k = 0; k < 16; ++k) {
      float4 av0 = *(const float4*)(As + k * 132 + ty * 4);
      float4 av1 = *(const float4*)(As + k * 132 + 64 + ty * 4);
      float4 bv = *(const float4*)(Bs + k * 64 + tx * 4);
      float x0[4] = {av0.x, av0.y, av0.z, av0.w};
      float x1[4] = {av1.x, av1.y, av1.z, av1.w};
      float c[4] = {bv.x, bv.y, bv.z, bv.w};
#pragma unroll
      for (int i = 0; i < 4; ++i)
#pragma unroll
        for (int j = 0; j < 4; ++j) {
          accA[i][j] = fmaf(x0[i], c[j], accA[i][j]);
          accB[i][j] = fmaf(x1[i], c[j], accB[i][j]);
        }
    }
  }
#pragma unroll
  for (int i = 0; i < 4; ++i) {
    size_t rA = (size_t)(m0 + ty * 4 + i);
    size_t rB = (size_t)(m0 + 64 + ty * 4 + i);
    *(float4*)(O + rA * 384 + n0 + tx * 4) = make_float4(accA[i][0], accA[i][1], accA[i][2], accA[i][3]);
    *(float4*)(O + rB * 384 + n0 + tx * 4) = make_float4(accB[i][0], accB[i][1], accB[i][2], accB[i][3]);
  }
}

// ---------------- kernel 3: 3-way K=192 group-sliced GEMM, 128x128 tile --------------
// R22: 128x128 (was 128x64). 576 blocks; per k-step 64 fma / 4 ds_read_b128.
// Each output element's k0-then-k fmaf chain unchanged => bit-identical.
__global__ __launch_bounds__(256) void gemm_pq3(const float* __restrict__ voff,
    const float* __restrict__ qp, const float* __restrict__ qin,
    const float* __restrict__ Woff1, const float* __restrict__ boff1,
    const float* __restrict__ Wv,
    float* __restrict__ P, float* __restrict__ Q, float* __restrict__ VW) {
  __shared__ float As[16 * 132];
  __shared__ float Bs[16 * 128];
  int tid = threadIdx.x;
  int m0 = blockIdx.x * 128, n0 = blockIdx.y * 128, z = blockIdx.z;
  int bg = m0 >> 10; int b = bg >> 1; int g = bg & 1; int ml0 = m0 & 1023;
  const float* Abase; const float* Bbase; const float* bias; float* Out; int bog;
  if (z == 0)      { Abase = voff; Bbase = Woff1;             bias = nullptr; Out = P;  bog = 0; }
  else if (z == 1) { Abase = qp;   Bbase = Woff1 + 192 * 384; bias = boff1;   Out = Q;  bog = 0; }
  else             { Abase = qin;  Bbase = Wv;                bias = nullptr; Out = VW; bog = 192 * 384; }
  const float* A = Abase + (size_t)b * 1024 * 384 + g * 192;
  const float* B = Bbase + (size_t)g * bog;
  int arow = tid >> 1, akq = (tid & 1) * 8;
  int lk = tid >> 4, ln8 = (tid & 15) * 8;
  int tx = tid & 15, ty = tid >> 4;
  float a11[4][4] = {{0.f}}, a21[4][4] = {{0.f}};
  float a12[4][4] = {{0.f}}, a22[4][4] = {{0.f}};
  for (int k0 = 0; k0 < 192; k0 += 16) {
    float4 a0 = *(const float4*)(A + (size_t)(ml0 + arow) * 384 + k0 + akq);
    float4 a1 = *(const float4*)(A + (size_t)(ml0 + arow) * 384 + k0 + akq + 4);
    float4 b0 = *(const float4*)(B + (size_t)(k0 + lk) * 384 + n0 + ln8);
    float4 b1 = *(const float4*)(B + (size_t)(k0 + lk) * 384 + n0 + ln8 + 4);
    __syncthreads();
    As[(akq + 0) * 132 + arow] = a0.x; As[(akq + 1) * 132 + arow] = a0.y;
    As[(akq + 2) * 132 + arow] = a0.z; As[(akq + 3) * 132 + arow] = a0.w;
    As[(akq + 4) * 132 + arow] = a1.x; As[(akq + 5) * 132 + arow] = a1.y;
    As[(akq + 6) * 132 + arow] = a1.z; As[(akq + 7) * 132 + arow] = a1.w;
    *(float4*)(Bs + lk * 128 + ln8) = b0;
    *(float4*)(Bs + lk * 128 + ln8 + 4) = b1;
    __syncthreads();
#pragma unroll
    for (int k = 0; k < 16; ++k) {
      float4 av0 = *(const float4*)(As + k * 132 + ty * 4);
      float4 av1 = *(const float4*)(As + k * 132 + 64 + ty * 4);
      float4 bv1 = *(const float4*)(Bs + k * 128 + tx * 4);
      float4 bv2 = *(const float4*)(Bs + k * 128 + 64 + tx * 4);
      float x0[4] = {av0.x, av0.y, av0.z, av0.w};
      float x1[4] = {av1.x, av1.y, av1.z, av1.w};
      float c1[4] = {bv1.x, bv1.y, bv1.z, bv1.w};
      float c2[4] = {bv2.x, bv2.y, bv2.z, bv2.w};
#pragma unroll
      for (int i = 0; i < 4; ++i)
#pragma unroll
        for (int j = 0; j < 4; ++j) {
          a11[i][j] = fmaf(x0[i], c1[j], a11[i][j]);
          a21[i][j] = fmaf(x1[i], c1[j], a21[i][j]);
          a12[i][j] = fmaf(x0[i], c2[j], a12[i][j]);
          a22[i][j] = fmaf(x1[i], c2[j], a22[i][j]);
        }
    }
  }
  float bbA[4] = {0.f, 0.f, 0.f, 0.f}, bbB[4] = {0.f, 0.f, 0.f, 0.f};
  if (bias) {
    bbA[0] = bias[n0 + tx * 4 + 0]; bbA[1] = bias[n0 + tx * 4 + 1];
    bbA[2] = bias[n0 + tx * 4 + 2]; bbA[3] = bias[n0 + tx * 4 + 3];
    bbB[0] = bias[n0 + 64 + tx * 4 + 0]; bbB[1] = bias[n0 + 64 + tx * 4 + 1];
    bbB[2] = bias[n0 + 64 + tx * 4 + 2]; bbB[3] = bias[n0 + 64 + tx * 4 + 3];
  }
#pragma unroll
  for (int i = 0; i < 4; ++i) {
    size_t rowA = (size_t)(m0 + ty * 4 + i);
    size_t rowB = (size_t)(m0 + 64 + ty * 4 + i);
    *(float4*)(Out + rowA * 384 + n0 + tx * 4) =
        make_float4(a11[i][0] + bbA[0], a11[i][1] + bbA[1], a11[i][2] + bbA[2], a11[i][3] + bbA[3]);
    *(float4*)(Out + rowB * 384 + n0 + tx * 4) =
        make_float4(a21[i][0] + bbA[0], a21[i][1] + bbA[1], a21[i][2] + bbA[2], a21[i][3] + bbA[3]);
    *(float4*)(Out + rowA * 384 + n0 + 64 + tx * 4) =
        make_float4(a12[i][0] + bbB[0], a12[i][1] + bbB[1], a12[i][2] + bbB[2], a12[i][3] + bbB[3]);
    *(float4*)(Out + rowB * 384 + n0 + 64 + tx * 4) =
        make_float4(a22[i][0] + bbB[0], a22[i][1] + bbB[1], a22[i][2] + bbB[2], a22[i][3] + bbB[3]);
  }
}

// ---------------- kernel 4: h = P[idx]+Q -> LN -> GELU -> @W_off2 -> tanh -> shift ---
// R13 body (verbatim; 4 rows/wave, 256 threads) + R20 XCD swizzle.
__global__ __launch_bounds__(256) void offset_assemble(const float* __restrict__ P,
    const float* __restrict__ Q, const int* __restrict__ idx,
    const float* __restrict__ lng, const float* __restrict__ lnb,
    const float* __restrict__ W2, const float* __restrict__ qpos,
    const float* __restrict__ sc, float* __restrict__ sp) {
  int bid = blockIdx.x;
  int bn = ((bid & 7) << 10) | (bid >> 3);   // bg*1024 + n  (8192 blocks)
  int wid = threadIdx.x >> 6, lane = threadIdx.x & 63;
  int n = bn & 1023, bg = bn >> 10, b = bg >> 1;
  int k0 = wid * 4;
  const int* idxr = idx + (((b << 10) + n) << 4) + k0;
  int mi[4];
#pragma unroll
  for (int r = 0; r < 4; ++r) mi[r] = idxr[r];
  const float* Qr = Q + ((size_t)bg * 1024 + n) * 384;
  const float* Pr[4];
#pragma unroll
  for (int r = 0; r < 4; ++r) Pr[r] = P + ((size_t)bg * 1024 + mi[r]) * 384;

  float h[4][6];
  float s[4] = {0.f, 0.f, 0.f, 0.f}, s2[4] = {0.f, 0.f, 0.f, 0.f};
#pragma unroll
  for (int u = 0; u < 3; ++u) {
    int c = 2 * lane + 128 * u;
    float2 qv = *(const float2*)(Qr + c);
#pragma unroll
    for (int r = 0; r < 4; ++r) {
      float2 pv = *(const float2*)(Pr[r] + c);
      float h0 = pv.x + qv.x, h1 = pv.y + qv.y;
      h[r][2 * u] = h0; h[r][2 * u + 1] = h1;
      s[r] += h0 + h1;
      s2[r] = fmaf(h0, h0, s2[r]);
      s2[r] = fmaf(h1, h1, s2[r]);
    }
  }
#pragma unroll
  for (int off = 32; off > 0; off >>= 1) {  // 8 interleaved butterflies
#pragma unroll
    for (int r = 0; r < 4; ++r) {
      s[r]  += __shfl_xor(s[r], off);
      s2[r] += __shfl_xor(s2[r], off);
    }
  }
  float mu[4], rstd[4];
#pragma unroll
  for (int r = 0; r < 4; ++r) {
    mu[r] = s[r] * (1.0f / 384.0f);
    float var = s2[r] * (1.0f / 384.0f) - mu[r] * mu[r];
    rstd[r] = 1.0f / sqrtf(var + 1e-5f);
  }
  float o0[4] = {0.f, 0.f, 0.f, 0.f}, o1[4] = {0.f, 0.f, 0.f, 0.f}, o2[4] = {0.f, 0.f, 0.f, 0.f};
#pragma unroll
  for (int u = 0; u < 3; ++u) {
    int c = 2 * lane + 128 * u;
    float2 gv  = *(const float2*)(lng + c);
    float2 bv  = *(const float2*)(lnb + c);
    float2 w01 = *(const float2*)(W2 + (size_t)c * 3);      // [c][0],[c][1]
    float2 w23 = *(const float2*)(W2 + (size_t)c * 3 + 2);  // [c][2],[c+1][0]
    float2 w45 = *(const float2*)(W2 + (size_t)c * 3 + 4);  // [c+1][1],[c+1][2]
#pragma unroll
    for (int r = 0; r < 4; ++r) {
      float x0 = fmaf((h[r][2 * u] - mu[r]) * rstd[r], gv.x, bv.x);
      float x1 = fmaf((h[r][2 * u + 1] - mu[r]) * rstd[r], gv.y, bv.y);
      float g0 = x0 * fmaf(fast_erff(x0 * 0.70710678118654752f), 0.5f, 0.5f);
      float g1 = x1 * fmaf(fast_erff(x1 * 0.70710678118654752f), 0.5f, 0.5f);
      o0[r] = fmaf(g0, w01.x, o0[r]); o1[r] = fmaf(g0, w01.y, o1[r]); o2[r] = fmaf(g0, w23.x, o2[r]);
      o0[r] = fmaf(g1, w23.y, o0[r]); o1[r] = fmaf(g1, w45.x, o1[r]); o2[r] = fmaf(g1, w45.y, o2[r]);
    }
  }
#pragma unroll
  for (int off = 32; off > 0; off >>= 1) {  // 12 interleaved butterflies
#pragma unroll
    for (int r = 0; r < 4; ++r) {
      o0[r] += __shfl_xor(o0[r], off);
      o1[r] += __shfl_xor(o1[r], off);
      o2[r] += __shfl_xor(o2[r], off);
    }
  }
  if (lane < 3) {
    float scv = sc[(((b << 10) + n)) * 3 + lane];
#pragma unroll
    for (int r = 0; r < 4; ++r) {
      float o = (lane == 0) ? o0[r] : ((lane == 1) ? o1[r] : o2[r]);
      float off = tanhf(o);
      float p = qpos[((size_t)b * 1024 + mi[r]) * 3 + lane];
      int row = (bn << 4) + k0 + r;       // (bg*1024+n)*16+k
      sp[(size_t)row * 3 + lane] = p + off * scv;
    }
  }
}

// ---------------- kernel 5a: three_nn partial — 8 chunks of 128, 2 chains, 2048 blks -
// R18: value-half of the sorted-triple insert via v_min/v_med3 (bitwise-exact
// selection); index compares verbatim strict-<. Geometry frozen at R17.
__global__ __launch_bounds__(256) void three_nn_part(const float* __restrict__ spos,
    const float* __restrict__ qpos, float* __restrict__ part_d, int* __restrict__ part_i) {
  __shared__ float px[128], py[128], pz[128], pp[128];
  int bid = blockIdx.x;             // bg(3b) | qg(5b) | chunk(3b)
  int bg = bid >> 8;
  int qg = (bid >> 3) & 31;
  int c  = bid & 7;
  int b = bg >> 1;
  int j0 = c << 7;
  const float* pb = qpos + (size_t)b * 1024 * 3;
  int tid = threadIdx.x;
  if (tid < 128) {
    int j = j0 + tid;
    float x = pb[j * 3 + 0], y = pb[j * 3 + 1], z = pb[j * 3 + 2];
    px[tid] = x; py[tid] = y; pz[tid] = z; pp[tid] = x * x + y * y + z * z;
  }
  __syncthreads();
  int m0 = qg * 512;
  int mA = m0 + tid;
  int mB = mA + 256;
  const float* spA = spos + ((size_t)bg * 16384 + mA) * 3;
  const float* spB = spos + ((size_t)bg * 16384 + mB) * 3;
  float sxA = spA[0], syA = spA[1], szA = spA[2];
  float sxB = spB[0], syB = spB[1], szB = spB[2];
  float qqA = sxA * sxA + syA * syA + szA * szA;
  float qqB = sxB * sxB + syB * syB + szB * szB;
  float d0A = 3.4e38f, d1A = 3.4e38f, d2A = 3.4e38f; int i0A = 0, i1A = 0, i2A = 0;
  float d0B = 3.4e38f, d1B = 3.4e38f, d2B = 3.4e38f; int i0B = 0, i1B = 0, i2B = 0;
#pragma unroll 8
  for (int jj = 0; jj < 128; ++jj) {
    int j = j0 + jj;
    float cx = px[jj], cy = py[jj], cz = pz[jj], cw = pp[jj];
    float dtA = sxA * cx + syA * cy + szA * cz;
    float dA = (qqA + cw) - 2.0f * dtA;
    float dtB = sxB * cx + syB * cy + szB * cz;
    float dB = (qqB + cw) - 2.0f * dtB;
    {
      bool c0 = dA < d0A, c1 = dA < d1A, c2 = dA < d2A;
      int   ni2 = c1 ? i1A : (c2 ? j : i2A);
      int   ni1 = c0 ? i0A : (c1 ? j : i1A);
      float nd2 = __builtin_amdgcn_fmed3f(d1A, d2A, dA);  // == c1?d1:(c2?dA:d2)
      float nd1 = __builtin_amdgcn_fmed3f(d0A, d1A, dA);  // == c0?d0:(c1?dA:d1)
      d0A = fminf(d0A, dA);  i0A = c0 ? j : i0A;
      d1A = nd1; i1A = ni1; d2A = nd2; i2A = ni2;
    }
    {
      bool c0 = dB < d0B, c1 = dB < d1B, c2 = dB < d2B;
      int   ni2 = c1 ? i1B : (c2 ? j : i2B);
      int   ni1 = c0 ? i0B : (c1 ? j : i1B);
      float nd2 = __builtin_amdgcn_fmed3f(d1B, d2B, dB);
      float nd1 = __builtin_amdgcn_fmed3f(d0B, d1B, dB);
      d0B = fminf(d0B, dB);  i0B = c0 ? j : i0B;
      d1B = nd1; i1B = ni1; d2B = nd2; i2B = ni2;
    }
  }
  {
    size_t base = (((size_t)bg * 8 + c) * 16384 + mA) * 3;
    part_d[base + 0] = d0A; part_d[base + 1] = d1A; part_d[base + 2] = d2A;
    part_i[base + 0] = i0A; part_i[base + 1] = i1A; part_i[base + 2] = i2A;
  }
  {
    size_t base = (((size_t)bg * 8 + c) * 16384 + mB) * 3;
    part_d[base + 0] = d0B; part_d[base + 1] = d1B; part_d[base + 2] = d2B;
    part_i[base + 0] = i0B; part_i[base + 1] = i1B; part_i[base + 2] = i2B;
  }
}

// ---------------- kernel 5b: three_nn merge — insert 8 chunk triples in order --------
__global__ __launch_bounds__(256) void three_nn_merge(const float* __restrict__ part_d,
    const int* __restrict__ part_i, float* __restrict__ w3, int* __restrict__ i3) {
  int q = blockIdx.x * 256 + threadIdx.x;   // 0..131071: bg*16384+m
  int bg = q >> 14, m = q & 16383;
  size_t pb = (((size_t)bg * 8) * 16384 + m) * 3;
  float D0 = part_d[pb + 0], D1 = part_d[pb + 1], D2 = part_d[pb + 2];
  int   I0 = part_i[pb + 0], I1 = part_i[pb + 1], I2 = part_i[pb + 2];
#pragma unroll
  for (int c = 1; c < 8; ++c) {
    size_t base = (((size_t)bg * 8 + c) * 16384 + m) * 3;
#pragma unroll
    for (int s = 0; s < 3; ++s) {
      float dv = part_d[base + s];
      int   iv = part_i[base + s];
      bool c0 = dv < D0, c1 = dv < D1, c2 = dv < D2;
      float nd2 = c1 ? D1 : (c2 ? dv : D2);
      int   ni2 = c1 ? I1 : (c2 ? iv : I2);
      float nd1 = c0 ? D0 : (c1 ? dv : D1);
      int   ni1 = c0 ? I0 : (c1 ? iv : I1);
      D0 = c0 ? dv : D0;  I0 = c0 ? iv : I0;
      D1 = nd1; I1 = ni1; D2 = nd2; I2 = ni2;
    }
  }
  float t0 = sqrtf(fmaxf(D0, 0.f)), t1 = sqrtf(fmaxf(D1, 0.f)), t2 = sqrtf(fmaxf(D2, 0.f));
  float r0 = 1.0f / (t0 + 1e-8f), r1 = 1.0f / (t1 + 1e-8f), r2 = 1.0f / (t2 + 1e-8f);
  float inv = 1.0f / (r0 + r1 + r2);
  size_t base = ((size_t)bg * 16384 + m) * 3;
  w3[base + 0] = r0 * inv; w3[base + 1] = r1 * inv; w3[base + 2] = r2 * inv;
  i3[base + 0] = I0; i3[base + 1] = I1; i3[base + 2] = I2;
}

// ---------------- kernel 6: qkh GEMM, 128x64 tile (K=48 per head) --------------------
__global__ __launch_bounds__(256) void gemm_qkh(const float* __restrict__ qp,
    const float* __restrict__ Wk, float* __restrict__ qkh) {
  __shared__ float As[16 * 132];
  __shared__ float Bs[16 * 68];
  int tid = threadIdx.x;
  int m0 = blockIdx.x * 128, c0 = blockIdx.y * 64, h = blockIdx.z;
  int arow = tid >> 1, akq = (tid & 1) * 8;
  int lm = tid >> 2, lq = (tid & 3) * 4;
  int tx = tid & 15, ty = tid >> 4;
  float accA[4][4] = {{0.f}}, accB[4][4] = {{0.f}};
  for (int k0 = 0; k0 < 48; k0 += 16) {
    float4 a0 = *(const float4*)(qp + (size_t)(m0 + arow) * 384 + h * 48 + k0 + akq);
    float4 a1 = *(const float4*)(qp + (size_t)(m0 + arow) * 384 + h * 48 + k0 + akq + 4);
    float4 b4 = *(const float4*)(Wk + (size_t)(c0 + lm) * 384 + h * 48 + k0 + lq);
    __syncthreads();
    As[(akq + 0) * 132 + arow] = a0.x; As[(akq + 1) * 132 + arow] = a0.y;
    As[(akq + 2) * 132 + arow] = a0.z; As[(akq + 3) * 132 + arow] = a0.w;
    As[(akq + 4) * 132 + arow] = a1.x; As[(akq + 5) * 132 + arow] = a1.y;
    As[(akq + 6) * 132 + arow] = a1.z; As[(akq + 7) * 132 + arow] = a1.w;
    Bs[(lq + 0) * 68 + lm] = b4.x; Bs[(lq + 1) * 68 + lm] = b4.y;
    Bs[(lq + 2) * 68 + lm] = b4.z; Bs[(lq + 3) * 68 + lm] = b4.w;
    __syncthreads();
#pragma unroll
    for (int k = 0; k < 16; ++k) {
      float4 av0 = *(const float4*)(As + k * 132 + ty * 4);
      float4 av1 = *(const float4*)(As + k * 132 + 64 + ty * 4);
      float4 bv = *(const float4*)(Bs + k * 68 + tx * 4);
      float a0v[4] = {av0.x, av0.y, av0.z, av0.w};
      float a1v[4] = {av1.x, av1.y, av1.z, av1.w};
      float c[4] = {bv.x, bv.y, bv.z, bv.w};
#pragma unroll
      for (int i = 0; i < 4; ++i)
#pragma unroll
        for (int j = 0; j < 4; ++j) {
          accA[i][j] = fmaf(a0v[i], c[j], accA[i][j]);
          accB[i][j] = fmaf(a1v[i], c[j], accB[i][j]);
        }
    }
  }
#pragma unroll
  for (int i = 0; i < 4; ++i) {
    size_t rowA = (size_t)(m0 + ty * 4 + i);
    size_t rowB = (size_t)(m0 + 64 + ty * 4 + i);
    *(float4*)(qkh + (rowA * 8 + h) * 384 + c0 + tx * 4) =
        make_float4(accA[i][0], accA[i][1], accA[i][2], accA[i][3]);
    *(float4*)(qkh + (rowB * 8 + h) * 384 + c0 + tx * 4) =
        make_float4(accB[i][0], accB[i][1], accB[i][2], accB[i][3]);
  }
}

// ---------------- kernel 7: fused interp + logits + softmax + out_pre ----------------
__global__ __launch_bounds__(256) void attn_fuse2(const float* __restrict__ v,
    const float* __restrict__ w3, const int* __restrict__ i3,
    const float* __restrict__ qkh, const float* __restrict__ VW,
    float* __restrict__ opre) {
  __shared__ float A[16 * 388];      // interp rows [k][c]
  __shared__ float Bv[16 * 388];     // interpVW rows [k][c']
  __shared__ float wk[16][2][3];
  __shared__ int ik[16][2][3];
  __shared__ float attnw[8 * 16];
  __shared__ float lpart[2][128];
  int tid = threadIdx.x;
  // XCD-aware swizzle: batch b -> XCD pair {2b, 2b+1} (round-robin dispatch assumed)
  int blk = blockIdx.x;
  int b = (blk & 7) >> 1;
  int n = ((blk & 1) << 9) | (blk >> 3);
  int bn = (b << 10) | n;
  if (tid < 96) {
    int k = tid / 6; int rem = tid % 6; int g = rem / 3; int s = rem % 3;
    size_t base = ((size_t)(b * 2 + g) * 16384 + n * 16 + k) * 3 + s;
    wk[k][g][s] = w3[base];
    ik[k][g][s] = i3[base];
  }
  __syncthreads();
  {  // build interp rows A[k][c] and interpVW rows Bv[k][c']; chunks c=(tid&15)*4+64u
    int r = tid >> 4;
    int cL = (tid & 15) * 4;
    const float* vr[2][3]; const float* wr[2][3];
#pragma unroll
    for (int g = 0; g < 2; ++g)
#pragma unroll
      for (int s = 0; s < 3; ++s) {
        vr[g][s] = v + ((size_t)b * 1024 + ik[r][g][s]) * 384;
        wr[g][s] = VW + ((size_t)(b * 2 + g) * 1024 + ik[r][g][s]) * 384;
      }
    float u0 = wk[r][0][0], u1 = wk[r][0][1], u2 = wk[r][0][2];
    float y0 = wk[r][1][0], y1 = wk[r][1][1], y2 = wk[r][1][2];
#pragma unroll
    for (int u = 0; u < 6; ++u) {
      int c = cL + 64 * u;
      int g = (u >= 3) ? 1 : 0;
      float w0 = wk[r][g][0], w1 = wk[r][g][1], w2 = wk[r][g][2];
      float4 f0 = *(const float4*)(vr[g][0] + c);
      float4 f1 = *(const float4*)(vr[g][1] + c);
      float4 f2 = *(const float4*)(vr[g][2] + c);
      float4 o;
      o.x = w0 * f0.x + w1 * f1.x + w2 * f2.x;
      o.y = w0 * f0.y + w1 * f1.y + w2 * f2.y;
      o.z = w0 * f0.z + w1 * f1.z + w2 * f2.z;
      o.w = w0 * f0.w + w1 * f1.w + w2 * f2.w;
      *(float4*)(A + r * 388 + c) = o;
      float4 a0 = *(const float4*)(wr[0][0] + c);
      float4 a1 = *(const float4*)(wr[0][1] + c);
      float4 a2 = *(const float4*)(wr[0][2] + c);
      float4 b0 = *(const float4*)(wr[1][0] + c);
      float4 b1 = *(const float4*)(wr[1][1] + c);
      float4 b2 = *(const float4*)(wr[1][2] + c);
      float4 p;
      p.x = u0 * a0.x + u1 * a1.x + u2 * a2.x + y0 * b0.x + y1 * b1.x + y2 * b2.x;
      p.y = u0 * a0.y + u1 * a1.y + u2 * a2.y + y0 * b0.y + y1 * b1.y + y2 * b2.y;
      p.z = u0 * a0.z + u1 * a1.z + u2 * a2.z + y0 * b0.z + y1 * b1.z + y2 * b2.z;
      p.w = u0 * a0.w + u1 * a1.w + u2 * a2.w + y0 * b0.w + y1 * b1.w + y2 * b2.w;
      *(float4*)(Bv + r * 388 + c) = p;
    }
  }
  __syncthreads();
  {  // logits with all 256 threads: (k,h,half) half-dots, then combine
    int r = tid & 15, h = (tid >> 4) & 7, half = tid >> 7;
    const float* qr = qkh + ((size_t)bn * 8 + h) * 384 + half * 192;
    const float* ar = A + r * 388 + half * 192;
    float acc = 0.f;
    for (int c = 0; c < 192; c += 4) {
      float4 av = *(const float4*)(ar + c);
      float4 qv = *(const float4*)(qr + c);
      acc += av.x * qv.x + av.y * qv.y + av.z * qv.z + av.w * qv.w;
    }
    lpart[half][h * 16 + r] = acc;
  }
  __syncthreads();
  if (tid < 128) attnw[tid] = (lpart[0][tid] + lpart[1][tid]) * ATTN_SCALE;
  __syncthreads();
  if (tid < 8) {  // softmax over k
    int h = tid;
    float m = -3.4e38f;
    for (int k = 0; k < 16; ++k) m = fmaxf(m, attnw[h * 16 + k]);
    float s = 0.f;
    for (int k = 0; k < 16; ++k) { float e = expf(attnw[h * 16 + k] - m); attnw[h * 16 + k] = e; s += e; }
    float inv = 1.0f / s;
    for (int k = 0; k < 16; ++k) attnw[h * 16 + k] *= inv;
  }
  __syncthreads();
  {  // out_pre[c'] = sum_k attn[h(c'),k] * Bv[k][c']
#pragma unroll
    for (int u = 0; u < 2; ++u) {
      int c = tid + 256 * u;
      if (c < 384) {
        int h = c / 48;
        float s = 0.f;
#pragma unroll
        for (int k = 0; k < 16; ++k) s = fmaf(attnw[h * 16 + k], Bv[k * 388 + c], s);
        opre[(size_t)bn * 384 + c] = s;
      }
    }
  }
}

// ---------------- kernel 9: out = out_pre @ Wp + bp, 64x64 tile ----------------------
// R21: 64x64 tiles (384 blocks); per-element k-chain unchanged => bit-identical.
__global__ __launch_bounds__(256) void gemm_final(const float* __restrict__ Ain,
    const float* __restrict__ Wp, const float* __restrict__ bp,
    float* __restrict__ Out) {
  __shared__ float As[16 * 68];
  __shared__ float Bs[16 * 64];
  int tid = threadIdx.x;
  int m0 = blockIdx.x * 64, n0 = blockIdx.y * 64;
  int arow = tid >> 2, akq = (tid & 3) * 4;
  int lk = tid >> 4, ln4 = (tid & 15) * 4;
  int tx = tid & 15, ty = tid >> 4;
  float acc[4][4] = {{0.f}};
  for (int k0 = 0; k0 < 384; k0 += 16) {
    float4 a0 = *(const float4*)(Ain + (size_t)(m0 + arow) * 384 + k0 + akq);
    float4 b4 = *(const float4*)(Wp + (size_t)(k0 + lk) * 384 + n0 + ln4);
    __syncthreads();
    As[(akq + 0) * 68 + arow] = a0.x; As[(akq + 1) * 68 + arow] = a0.y;
    As[(akq + 2) * 68 + arow] = a0.z; As[(akq + 3) * 68 + arow] = a0.w;
    *(float4*)(Bs + lk * 64 + ln4) = b4;
    __syncthreads();
#pragma unroll
    for (int k = 0; k < 16; ++k) {
      float4 av = *(const float4*)(As + k * 68 + ty * 4);
      float4 bv = *(const float4*)(Bs + k * 64 + tx * 4);
      float a0v[4] = {av.x, av.y, av.z, av.w};
      float c[4] = {bv.x, bv.y, bv.z, bv.w};
#pragma unroll
      for (int i = 0; i < 4; ++i)
#pragma unroll
        for (int j = 0; j < 4; ++j) {
          acc[i][j] = fmaf(a0v[i], c[j], acc[i][j]);
        }
    }
  }
  float bb[4];
  bb[0] = bp[n0 + tx * 4 + 0]; bb[1] = bp[n0 + tx * 4 + 1];
  bb[2] = bp[n0 + tx * 4 + 2]; bb[3] = bp[n0 + tx * 4 + 3];
#pragma unroll
  for (int i = 0; i < 4; ++i) {
    size_t row = (size_t)(m0 + ty * 4 + i);
    *(float4*)(Out + row * 384 + n0 + tx * 4) =
        make_float4(acc[i][0] + bb[0], acc[i][1] + bb[1], acc[i][2] + bb[2], acc[i][3] + bb[3]);
  }
}

extern "C" void kernel_launch(void* const* d_in, const int* in_sizes, int n_in,
                              void* d_out, int out_size, void* d_ws, size_t ws_size,
                              hipStream_t stream) {
  (void)in_sizes; (void)n_in; (void)out_size; (void)ws_size;  // needs ~143 MB ws
  const float* q     = (const float*)d_in[0];
  const float* qpos  = (const float*)d_in[1];
  const float* Wq    = (const float*)d_in[2];
  const float* Wk    = (const float*)d_in[3];
  const float* Wv    = (const float*)d_in[4];
  const float* Wvoff = (const float*)d_in[5];
  const float* Woff1 = (const float*)d_in[6];
  const float* boff1 = (const float*)d_in[7];
  const float* lng   = (const float*)d_in[8];
  const float* lnb   = (const float*)d_in[9];
  const float* Woff2 = (const float*)d_in[10];
  const float* Wp    = (const float*)d_in[11];
  const float* bp    = (const float*)d_in[12];
  float* out = (float*)d_out;
  float* ws = (float*)d_ws;
  int*   idxb = (int*)(ws + OFF_IDX);
  float* sc   = ws + OFF_SC;
  float* qp   = ws + OFF_QP;
  float* voff = ws + OFF_VOFF;
  float* P    = ws + OFF_P;
  float* Q    = ws + OFF_Q;
  float* spos = ws + OFF_SP;
  float* w3   = ws + OFF_W3;
  int*   i3   = (int*)(ws + OFF_I3);
  float* qkh  = ws + OFF_QKH;
  float* VW   = ws + OFF_VW;
  float* opre = ws + OFF_OPRE;
  float* p3d  = ws + OFF_P3D;          // overlay on P (dead after offset_assemble)
  int*   p3i  = (int*)(ws + OFF_P3I);  // overlay on Q (dead after offset_assemble)

  knn_kernel<<<4096, 64, 0, stream>>>(qpos, idxb, sc);
  gemm_qp_voff<<<dim3(32, 6, 2), 256, 0, stream>>>(q, Wq, Wvoff, qp, voff);
  gemm_pq3<<<dim3(64, 3, 3), 256, 0, stream>>>(voff, qp, q, Woff1, boff1, Wv, P, Q, VW);
  offset_assemble<<<8192, 256, 0, stream>>>(P, Q, idxb, lng, lnb, Woff2, qpos, sc, spos);
  three_nn_part<<<2048, 256, 0, stream>>>(spos, qpos, p3d, p3i);
  three_nn_merge<<<512, 256, 0, stream>>>(p3d, p3i, w3, i3);
  gemm_qkh<<<dim3(32, 6, 8), 256, 0, stream>>>(qp, Wk, qkh);
  attn_fuse2<<<4096, 256, 0, stream>>>(q, w3, i3, qkh, VW, opre);
  gemm_final<<<dim3(64, 6), 256, 0, stream>>>(opre, Wp, bp, out);
}